// Round 3
// baseline (415.228 us; speedup 1.0000x reference)
//
#include <hip/hip_runtime.h>
#include <hip/hip_fp16.h>
#include <math.h>
#include <limits.h>

#define N_NODES 50000
#define N_EDGES 800000
#define N_GRAPHS 64
#define IN_CH 128
#define EMB 64
#define POOL_CHUNK 16   // 50000 = 16 * 3125 exactly
#define CPAD 32         // counts padded to one 128B line/node: [0]=count, [1]=weighted deg

// ---------- init: padded counts+degw=0, total=0, pool accumulators ----------
__global__ void init_k(int* counts, int* total, int* gmax, float* gsum, int* cnt) {
    int i = blockIdx.x * blockDim.x + threadIdx.x;
    if (i < N_NODES * CPAD) counts[i] = 0;   // zeroes degw too (0.0f bit pattern)
    if (i == 0) *total = 0;
    if (i < N_GRAPHS * EMB) { gmax[i] = INT_MIN; gsum[i] = 0.f; }
    if (i < N_GRAPHS) cnt[i] = 0;
}

// ---------- histogram: in-degree count + weighted degree (same cache line) ----------
__global__ void hist_k(const int* __restrict__ dst, const float* __restrict__ w,
                       int* counts, int* __restrict__ slot_in) {
    int e = blockIdx.x * blockDim.x + threadIdx.x;
    if (e >= N_EDGES) return;
    size_t base = (size_t)dst[e] * CPAD;
    slot_in[e] = atomicAdd(&counts[base], 1);
    atomicAdd((float*)&counts[base + 1], w[e]);
}

// ---------- CSR range allocation: wave-scan + one atomic per wave; dinv folded ----------
__global__ void alloc_k(const int* __restrict__ counts, int* __restrict__ row_start,
                        int* __restrict__ row_end, int* total, float* __restrict__ dinv) {
    int i = blockIdx.x * blockDim.x + threadIdx.x;
    int lane = threadIdx.x & 63;
    int c = (i < N_NODES) ? counts[(size_t)i * CPAD] : 0;
    int inc = c;
    for (int off = 1; off < 64; off <<= 1) {
        int v = __shfl_up(inc, off);
        if (lane >= off) inc += v;
    }
    int base;
    if (lane == 63) base = atomicAdd(total, inc);
    base = __shfl(base, 63);
    int excl = base + inc - c;
    if (i < N_NODES) {
        row_start[i] = excl;
        row_end[i] = excl + c;
        float d = 1.0f + __int_as_float(counts[(size_t)i * CPAD + 1]);  // + self-loop
        dinv[i] = d > 0.f ? rsqrtf(d) : 0.f;
    }
}

// ---------- scatter edges into CSR slots (atomic-free); store (src, raw w) ----------
// norm is never materialized: dinv[src] folded into stored features (GEMM epilogue),
// dinv[dst] folded into the aggregation epilogue.
__global__ void scatter_k(const int* __restrict__ src, const int* __restrict__ dst,
                          const float* __restrict__ w, const int* __restrict__ slot_in,
                          const int* __restrict__ row_start, int2* __restrict__ csr) {
    int e = blockIdx.x * blockDim.x + threadIdx.x;
    if (e >= N_EDGES) return;
    int d = dst[e];
    int slot = row_start[d] + slot_in[e];
    csr[slot] = make_int2(src[e], __float_as_int(w[e]));
}

// ---------- hs = dinv * (A @ W) : LDS-tiled, 64x64 output tile, 4x4 register tile ----------
// Output FP16 (hs rows are 128B = 2 cache lines/edge in the gather).
// HALF_IN: A itself is fp16 (layers 1-3 read the previous agg output) -- convert on stage.
template<int K, bool HALF_IN>
__global__ __launch_bounds__(256) void gemm_k(const void* __restrict__ A_,
                                              const float* __restrict__ W,
                                              const float* __restrict__ dinv,
                                              __half* __restrict__ out) {
    __shared__ float Al[64 * K];
    __shared__ float Wl[K * EMB];
    int tid = threadIdx.x;
    long rowBase = (long)blockIdx.x * 64;
    int validRows = (int)min((long)64, (long)N_NODES - rowBase);

    if constexpr (HALF_IN) {
        const __half* Ah = (const __half*)A_ + rowBase * K;
        for (int i = tid; i < validRows * (K / 4); i += 256) {
            int r = i / (K / 4), kc = i % (K / 4);
            const __half2* p = (const __half2*)(Ah + (long)r * K + 4 * kc);
            float2 lo = __half22float2(p[0]);
            float2 hi = __half22float2(p[1]);
            *(float4*)&Al[r * K + 4 * (kc ^ (r & 3))] = make_float4(lo.x, lo.y, hi.x, hi.y);
        }
    } else {
        const float4* Ag = (const float4*)((const float*)A_ + rowBase * K);
        for (int i = tid; i < validRows * (K / 4); i += 256) {
            int r = i / (K / 4), kc = i % (K / 4);
            float4 v = Ag[(long)r * (K / 4) + kc];
            *(float4*)&Al[r * K + 4 * (kc ^ (r & 3))] = v;
        }
    }
    const float4* Wg = (const float4*)W;
    float4* Wl4 = (float4*)Wl;
    for (int i = tid; i < K * EMB / 4; i += 256) Wl4[i] = Wg[i];
    __syncthreads();

    int tc = tid & 15, tr = tid >> 4;
    int r0 = tr * 4, c0 = tc * 4;
    float acc[4][4] = {};
#pragma unroll 2
    for (int k = 0; k < K; k += 4) {
        int kc = k >> 2;
        float4 a[4], w[4];
#pragma unroll
        for (int i = 0; i < 4; ++i)
            a[i] = *(const float4*)&Al[(r0 + i) * K + 4 * (kc ^ i)];
#pragma unroll
        for (int j = 0; j < 4; ++j)
            w[j] = *(const float4*)&Wl[(k + j) * EMB + c0];
#pragma unroll
        for (int i = 0; i < 4; ++i) {
            const float* ai = (const float*)&a[i];
#pragma unroll
            for (int kk = 0; kk < 4; ++kk) {
                float av = ai[kk];
                const float* wk = (const float*)&w[kk];
#pragma unroll
                for (int j = 0; j < 4; ++j) acc[i][j] += av * wk[j];
            }
        }
    }
#pragma unroll
    for (int i = 0; i < 4; ++i) {
        long row = rowBase + r0 + i;
        if (row < N_NODES) {
            float dv = dinv[row];
            __half2 p0 = __floats2half2_rn(dv * acc[i][0], dv * acc[i][1]);
            __half2 p1 = __floats2half2_rn(dv * acc[i][2], dv * acc[i][3]);
            uint2 u = make_uint2(*(unsigned int*)&p0, *(unsigned int*)&p1);
            *(uint2*)&out[row * EMB + c0] = u;   // 8B aligned: c0 % 4 == 0
        }
    }
}

// ---------- fused aggregation: self-loop + bias + CSR gather + tanh ----------
// one wave per node; lane = channel; 8 gathers in flight. hs rows are fp16
// (2 lines/edge); csr.y holds RAW edge weight; out = tanh(dinv*(hs_self + sum) + b).
// Output fp16 too (feeds next GEMM / pool). Structure otherwise proven (journal).
__global__ __launch_bounds__(256) void fused_agg_k(const __half* __restrict__ hs,
                                                   const int2* __restrict__ csr,
                                                   const int* __restrict__ row_start,
                                                   const int* __restrict__ row_end,
                                                   const float* __restrict__ dinv,
                                                   const float* __restrict__ b,
                                                   __half* __restrict__ out) {
    int node = (blockIdx.x * blockDim.x + threadIdx.x) >> 6;
    int lane = threadIdx.x & 63;
    if (node >= N_NODES) return;
    float di = dinv[node];
    float acc = __half2float(hs[(long)node * EMB + lane]);   // self term (dinv folded later)
    int e = row_start[node];
    int end = row_end[node];
    for (; e + 7 < end; e += 8) {
        int2 r[8];
        __half v[8];
#pragma unroll
        for (int i = 0; i < 8; ++i) r[i] = csr[e + i];
#pragma unroll
        for (int i = 0; i < 8; ++i) v[i] = hs[(long)r[i].x * EMB + lane];
#pragma unroll
        for (int i = 0; i < 8; ++i) acc += __int_as_float(r[i].y) * __half2float(v[i]);
    }
    for (; e + 3 < end; e += 4) {
        int2 r0 = csr[e], r1 = csr[e + 1], r2 = csr[e + 2], r3 = csr[e + 3];
        float v0 = __half2float(hs[(long)r0.x * EMB + lane]);
        float v1 = __half2float(hs[(long)r1.x * EMB + lane]);
        float v2 = __half2float(hs[(long)r2.x * EMB + lane]);
        float v3 = __half2float(hs[(long)r3.x * EMB + lane]);
        acc += __int_as_float(r0.y) * v0;
        acc += __int_as_float(r1.y) * v1;
        acc += __int_as_float(r2.y) * v2;
        acc += __int_as_float(r3.y) * v3;
    }
    for (; e < end; ++e) {
        int2 r0 = csr[e];
        acc += __int_as_float(r0.y) * __half2float(hs[(long)r0.x * EMB + lane]);
    }
    float o = tanhf(di * acc + b[lane]);
    __half oh = __float2half(o);
    __builtin_nontemporal_store(*(unsigned short*)&oh,
                                (unsigned short*)&out[(long)node * EMB + lane]);
}

// ---------- pooling ----------
__device__ inline int f2ord(float x) {
    int bb = __float_as_int(x);
    return bb >= 0 ? bb : (bb ^ 0x7fffffff);
}
__device__ inline float ord2f(int k) {
    return __int_as_float(k >= 0 ? k : (k ^ 0x7fffffff));
}

// wave = 16 contiguous nodes (batch sorted); lane = channel.
__global__ __launch_bounds__(256) void pool_k(const __half* __restrict__ h,
                                              const int* __restrict__ batch,
                                              int* gmax, float* gsum, int* cnt) {
    int wave = (blockIdx.x * blockDim.x + threadIdx.x) >> 6;
    int lane = threadIdx.x & 63;
    int start = wave * POOL_CHUNK;
    if (start >= N_NODES) return;   // 50000 % 16 == 0 -> full chunks always
    int bsel = (lane < POOL_CHUNK) ? batch[start + lane] : 0;
    float v[POOL_CHUNK];
#pragma unroll
    for (int i = 0; i < POOL_CHUNK; ++i)
        v[i] = __half2float(h[(long)(start + i) * EMB + lane]);
    int curg = __shfl(bsel, 0);
    float mx = -INFINITY, sm = 0.f;
    int ct = 0;
#pragma unroll
    for (int i = 0; i < POOL_CHUNK; ++i) {
        int g = __shfl(bsel, i);
        if (g != curg) {
            atomicMax(&gmax[curg * EMB + lane], f2ord(mx));
            atomicAdd(&gsum[curg * EMB + lane], sm);
            if (lane == 0) atomicAdd(&cnt[curg], ct);
            curg = g; mx = -INFINITY; sm = 0.f; ct = 0;
        }
        mx = fmaxf(mx, v[i]);
        sm += v[i];
        ++ct;
    }
    atomicMax(&gmax[curg * EMB + lane], f2ord(mx));
    atomicAdd(&gsum[curg * EMB + lane], sm);
    if (lane == 0) atomicAdd(&cnt[curg], ct);
}

__global__ void final_k(const int* __restrict__ gmax, const float* __restrict__ gsum,
                        const int* __restrict__ cnt, const float* __restrict__ Wout,
                        const float* __restrict__ bout, float* __restrict__ out) {
    int g = threadIdx.x;
    if (g >= N_GRAPHS) return;
    float c = fmaxf((float)cnt[g], 1.0f);
    float acc = bout[0];
    for (int ch = 0; ch < EMB; ++ch) {
        acc += ord2f(gmax[g * EMB + ch]) * Wout[ch]
             + (gsum[g * EMB + ch] / c) * Wout[EMB + ch];
    }
    out[g] = acc;
}

extern "C" void kernel_launch(void* const* d_in, const int* in_sizes, int n_in,
                              void* d_out, int out_size, void* d_ws, size_t ws_size,
                              hipStream_t stream) {
    const float* x         = (const float*)d_in[0];
    const int*   edge_idx  = (const int*)d_in[1];
    const float* edge_attr = (const float*)d_in[2];
    const int*   batch     = (const int*)d_in[3];
    const float* W0 = (const float*)d_in[4];
    const float* b0 = (const float*)d_in[5];
    const float* W1 = (const float*)d_in[6];
    const float* b1 = (const float*)d_in[7];
    const float* W2 = (const float*)d_in[8];
    const float* b2 = (const float*)d_in[9];
    const float* W3 = (const float*)d_in[10];
    const float* b3 = (const float*)d_in[11];
    const float* Wout = (const float*)d_in[12];
    const float* bout = (const float*)d_in[13];
    float* out = (float*)d_out;

    const int* src = edge_idx;            // edge_index[0]
    const int* dst = edge_idx + N_EDGES;  // edge_index[1]

    // workspace layout (~33 MB)
    char* ws = (char*)d_ws;
    float*  dinv      = (float*)ws;  ws += (size_t)N_NODES * sizeof(float);
    int*    counts    = (int*)ws;    ws += (size_t)N_NODES * CPAD * sizeof(int);
    int*    row_start = (int*)ws;    ws += (size_t)N_NODES * sizeof(int);
    int*    row_end   = (int*)ws;    ws += (size_t)N_NODES * sizeof(int);
    int*    slot_in   = (int*)ws;    ws += (size_t)N_EDGES * sizeof(int);
    int*    total     = (int*)ws;    ws += 4 * sizeof(int);  // keep 16B alignment
    int2*   csr       = (int2*)ws;   ws += (size_t)N_EDGES * sizeof(int2);
    __half* bufL      = (__half*)ws; ws += (size_t)N_NODES * EMB * sizeof(__half);
    __half* bufH      = (__half*)ws; ws += (size_t)N_NODES * EMB * sizeof(__half);
    int*    gmax      = (int*)ws;    ws += N_GRAPHS * EMB * sizeof(int);
    float*  gsum      = (float*)ws;  ws += N_GRAPHS * EMB * sizeof(float);
    int*    cnt       = (int*)ws;    ws += N_GRAPHS * sizeof(int);

    const int nodeB = (N_NODES + 255) / 256;
    const int edgeB = (N_EDGES + 255) / 256;
    const int waveB = (N_NODES * 64 + 255) / 256;  // one wave per node
    const int gemmB = (N_NODES + 63) / 64;         // 782 blocks, 64-row tiles
    const int initB = (N_NODES * CPAD + 255) / 256;

    // CSR precompute (norm fully folded: dinv[src] -> GEMM epilogue, dinv[dst] -> agg)
    init_k<<<initB, 256, 0, stream>>>(counts, total, gmax, gsum, cnt);
    hist_k<<<edgeB, 256, 0, stream>>>(dst, edge_attr, counts, slot_in);
    alloc_k<<<nodeB, 256, 0, stream>>>(counts, row_start, row_end, total, dinv);
    scatter_k<<<edgeB, 256, 0, stream>>>(src, dst, edge_attr, slot_in, row_start, csr);

    const float* Wl[4] = {W0, W1, W2, W3};
    const float* bl[4] = {b0, b1, b2, b3};
    for (int l = 0; l < 4; ++l) {
        if (l == 0) gemm_k<IN_CH, false><<<gemmB, 256, 0, stream>>>(x, Wl[0], dinv, bufL);
        else        gemm_k<EMB, true>   <<<gemmB, 256, 0, stream>>>(bufH, Wl[l], dinv, bufL);
        fused_agg_k<<<waveB, 256, 0, stream>>>(bufL, csr, row_start, row_end, dinv, bl[l], bufH);
    }

    pool_k<<<(((N_NODES + POOL_CHUNK - 1) / POOL_CHUNK) * 64 + 255) / 256, 256, 0, stream>>>(
        bufH, batch, gmax, gsum, cnt);
    final_k<<<1, 64, 0, stream>>>(gmax, gsum, cnt, Wout, bout, out);
}

// Round 4
// 375.328 us; speedup vs baseline: 1.1063x; 1.1063x over previous
//
#include <hip/hip_runtime.h>
#include <hip/hip_fp16.h>
#include <math.h>
#include <limits.h>

#define N_NODES 50000
#define N_EDGES 800000
#define N_GRAPHS 64
#define IN_CH 128
#define EMB 64
#define POOL_CHUNK 16   // 50000 = 16 * 3125 exactly
#define CPAD64 16       // one 128B line per node: single u64 = (count<<44) | wsum_fx24
#define CNT_SHIFT 44
#define FX_SCALE 16777216.0f   // 2^24 fixed-point for edge weights (w in [0,1))

// ---------- init: packed counters=0, total=0, pool accumulators ----------
__global__ void init_k(unsigned long long* cnt64, int* total, int* gmax,
                       float* gsum, int* cnt) {
    int i = blockIdx.x * blockDim.x + threadIdx.x;
    if (i < N_NODES * CPAD64) cnt64[i] = 0ULL;
    if (i == 0) *total = 0;
    if (i < N_GRAPHS * EMB) { gmax[i] = INT_MIN; gsum[i] = 0.f; }
    if (i < N_GRAPHS) cnt[i] = 0;
}

// ---------- histogram: ONE packed 64-bit atomic per edge ----------
// high 20 bits: in-degree count (slot allocation); low 44 bits: sum of w in 2^-24
// fixed point (max realistic sum ~2^30, no overflow into count field).
__global__ void hist_k(const int* __restrict__ dst, const float* __restrict__ w,
                       unsigned long long* cnt64, int* __restrict__ slot_in) {
    int e = blockIdx.x * blockDim.x + threadIdx.x;
    if (e >= N_EDGES) return;
    unsigned long long fx = (unsigned long long)(w[e] * FX_SCALE + 0.5f);
    unsigned long long old = atomicAdd(&cnt64[(size_t)dst[e] * CPAD64],
                                       (1ULL << CNT_SHIFT) | fx);
    slot_in[e] = (int)(old >> CNT_SHIFT);
}

// ---------- CSR range allocation: wave-scan + one atomic per wave; dinv folded ----------
__global__ void alloc_k(const unsigned long long* __restrict__ cnt64,
                        int* __restrict__ row_start, int* __restrict__ row_end,
                        int* total, float* __restrict__ dinv) {
    int i = blockIdx.x * blockDim.x + threadIdx.x;
    int lane = threadIdx.x & 63;
    unsigned long long v = (i < N_NODES) ? cnt64[(size_t)i * CPAD64] : 0ULL;
    int c = (int)(v >> CNT_SHIFT);
    int inc = c;
    for (int off = 1; off < 64; off <<= 1) {
        int t = __shfl_up(inc, off);
        if (lane >= off) inc += t;
    }
    int base;
    if (lane == 63) base = atomicAdd(total, inc);
    base = __shfl(base, 63);
    int excl = base + inc - c;
    if (i < N_NODES) {
        row_start[i] = excl;
        row_end[i] = excl + c;
        float degw = (float)(v & ((1ULL << CNT_SHIFT) - 1)) * (1.0f / FX_SCALE);
        float d = 1.0f + degw;  // + self-loop weight 1
        dinv[i] = d > 0.f ? rsqrtf(d) : 0.f;
    }
}

// ---------- scatter edges into CSR slots (atomic-free); store (src, raw w) ----------
// norm is never materialized: dinv[src] folded into stored features (GEMM epilogue),
// dinv[dst] folded into the aggregation epilogue.
__global__ void scatter_k(const int* __restrict__ src, const int* __restrict__ dst,
                          const float* __restrict__ w, const int* __restrict__ slot_in,
                          const int* __restrict__ row_start, int2* __restrict__ csr) {
    int e = blockIdx.x * blockDim.x + threadIdx.x;
    if (e >= N_EDGES) return;
    int d = dst[e];
    int slot = row_start[d] + slot_in[e];
    csr[slot] = make_int2(src[e], __float_as_int(w[e]));
}

// ---------- hs = dinv * (A @ W) : LDS-tiled, 64x64 output tile, 4x4 register tile ----------
// Output FP16 (hs rows are 128B = 2 cache lines/edge in the gather).
// HALF_IN: A itself is fp16 (layers 1-3 read the previous agg output) -- convert on stage.
template<int K, bool HALF_IN>
__global__ __launch_bounds__(256) void gemm_k(const void* __restrict__ A_,
                                              const float* __restrict__ W,
                                              const float* __restrict__ dinv,
                                              __half* __restrict__ out) {
    __shared__ float Al[64 * K];
    __shared__ float Wl[K * EMB];
    int tid = threadIdx.x;
    long rowBase = (long)blockIdx.x * 64;
    int validRows = (int)min((long)64, (long)N_NODES - rowBase);

    if constexpr (HALF_IN) {
        const __half* Ah = (const __half*)A_ + rowBase * K;
        for (int i = tid; i < validRows * (K / 4); i += 256) {
            int r = i / (K / 4), kc = i % (K / 4);
            const __half2* p = (const __half2*)(Ah + (long)r * K + 4 * kc);
            float2 lo = __half22float2(p[0]);
            float2 hi = __half22float2(p[1]);
            *(float4*)&Al[r * K + 4 * (kc ^ (r & 3))] = make_float4(lo.x, lo.y, hi.x, hi.y);
        }
    } else {
        const float4* Ag = (const float4*)((const float*)A_ + rowBase * K);
        for (int i = tid; i < validRows * (K / 4); i += 256) {
            int r = i / (K / 4), kc = i % (K / 4);
            float4 v = Ag[(long)r * (K / 4) + kc];
            *(float4*)&Al[r * K + 4 * (kc ^ (r & 3))] = v;
        }
    }
    const float4* Wg = (const float4*)W;
    float4* Wl4 = (float4*)Wl;
    for (int i = tid; i < K * EMB / 4; i += 256) Wl4[i] = Wg[i];
    __syncthreads();

    int tc = tid & 15, tr = tid >> 4;
    int r0 = tr * 4, c0 = tc * 4;
    float acc[4][4] = {};
#pragma unroll 2
    for (int k = 0; k < K; k += 4) {
        int kc = k >> 2;
        float4 a[4], w[4];
#pragma unroll
        for (int i = 0; i < 4; ++i)
            a[i] = *(const float4*)&Al[(r0 + i) * K + 4 * (kc ^ i)];
#pragma unroll
        for (int j = 0; j < 4; ++j)
            w[j] = *(const float4*)&Wl[(k + j) * EMB + c0];
#pragma unroll
        for (int i = 0; i < 4; ++i) {
            const float* ai = (const float*)&a[i];
#pragma unroll
            for (int kk = 0; kk < 4; ++kk) {
                float av = ai[kk];
                const float* wk = (const float*)&w[kk];
#pragma unroll
                for (int j = 0; j < 4; ++j) acc[i][j] += av * wk[j];
            }
        }
    }
#pragma unroll
    for (int i = 0; i < 4; ++i) {
        long row = rowBase + r0 + i;
        if (row < N_NODES) {
            float dv = dinv[row];
            __half2 p0 = __floats2half2_rn(dv * acc[i][0], dv * acc[i][1]);
            __half2 p1 = __floats2half2_rn(dv * acc[i][2], dv * acc[i][3]);
            uint2 u = make_uint2(*(unsigned int*)&p0, *(unsigned int*)&p1);
            *(uint2*)&out[row * EMB + c0] = u;   // 8B aligned: c0 % 4 == 0
        }
    }
}

// ---------- fused aggregation: self-loop + bias + CSR gather + tanh ----------
// one wave per node; lane = channel; 8 gathers in flight. hs rows are fp16
// (2 lines/edge); csr.y holds RAW edge weight; out = tanh(dinv*(hs_self + sum) + b).
// Output fp16 too (feeds next GEMM / pool). Structure otherwise proven (journal).
__global__ __launch_bounds__(256) void fused_agg_k(const __half* __restrict__ hs,
                                                   const int2* __restrict__ csr,
                                                   const int* __restrict__ row_start,
                                                   const int* __restrict__ row_end,
                                                   const float* __restrict__ dinv,
                                                   const float* __restrict__ b,
                                                   __half* __restrict__ out) {
    int node = (blockIdx.x * blockDim.x + threadIdx.x) >> 6;
    int lane = threadIdx.x & 63;
    if (node >= N_NODES) return;
    float di = dinv[node];
    float acc = __half2float(hs[(long)node * EMB + lane]);   // self term (dinv folded later)
    int e = row_start[node];
    int end = row_end[node];
    for (; e + 7 < end; e += 8) {
        int2 r[8];
        __half v[8];
#pragma unroll
        for (int i = 0; i < 8; ++i) r[i] = csr[e + i];
#pragma unroll
        for (int i = 0; i < 8; ++i) v[i] = hs[(long)r[i].x * EMB + lane];
#pragma unroll
        for (int i = 0; i < 8; ++i) acc += __int_as_float(r[i].y) * __half2float(v[i]);
    }
    for (; e + 3 < end; e += 4) {
        int2 r0 = csr[e], r1 = csr[e + 1], r2 = csr[e + 2], r3 = csr[e + 3];
        float v0 = __half2float(hs[(long)r0.x * EMB + lane]);
        float v1 = __half2float(hs[(long)r1.x * EMB + lane]);
        float v2 = __half2float(hs[(long)r2.x * EMB + lane]);
        float v3 = __half2float(hs[(long)r3.x * EMB + lane]);
        acc += __int_as_float(r0.y) * v0;
        acc += __int_as_float(r1.y) * v1;
        acc += __int_as_float(r2.y) * v2;
        acc += __int_as_float(r3.y) * v3;
    }
    for (; e < end; ++e) {
        int2 r0 = csr[e];
        acc += __int_as_float(r0.y) * __half2float(hs[(long)r0.x * EMB + lane]);
    }
    float o = tanhf(di * acc + b[lane]);
    __half oh = __float2half(o);
    __builtin_nontemporal_store(*(unsigned short*)&oh,
                                (unsigned short*)&out[(long)node * EMB + lane]);
}

// ---------- pooling ----------
__device__ inline int f2ord(float x) {
    int bb = __float_as_int(x);
    return bb >= 0 ? bb : (bb ^ 0x7fffffff);
}
__device__ inline float ord2f(int k) {
    return __int_as_float(k >= 0 ? k : (k ^ 0x7fffffff));
}

// wave = 16 contiguous nodes (batch sorted); lane = channel.
__global__ __launch_bounds__(256) void pool_k(const __half* __restrict__ h,
                                              const int* __restrict__ batch,
                                              int* gmax, float* gsum, int* cnt) {
    int wave = (blockIdx.x * blockDim.x + threadIdx.x) >> 6;
    int lane = threadIdx.x & 63;
    int start = wave * POOL_CHUNK;
    if (start >= N_NODES) return;   // 50000 % 16 == 0 -> full chunks always
    int bsel = (lane < POOL_CHUNK) ? batch[start + lane] : 0;
    float v[POOL_CHUNK];
#pragma unroll
    for (int i = 0; i < POOL_CHUNK; ++i)
        v[i] = __half2float(h[(long)(start + i) * EMB + lane]);
    int curg = __shfl(bsel, 0);
    float mx = -INFINITY, sm = 0.f;
    int ct = 0;
#pragma unroll
    for (int i = 0; i < POOL_CHUNK; ++i) {
        int g = __shfl(bsel, i);
        if (g != curg) {
            atomicMax(&gmax[curg * EMB + lane], f2ord(mx));
            atomicAdd(&gsum[curg * EMB + lane], sm);
            if (lane == 0) atomicAdd(&cnt[curg], ct);
            curg = g; mx = -INFINITY; sm = 0.f; ct = 0;
        }
        mx = fmaxf(mx, v[i]);
        sm += v[i];
        ++ct;
    }
    atomicMax(&gmax[curg * EMB + lane], f2ord(mx));
    atomicAdd(&gsum[curg * EMB + lane], sm);
    if (lane == 0) atomicAdd(&cnt[curg], ct);
}

__global__ void final_k(const int* __restrict__ gmax, const float* __restrict__ gsum,
                        const int* __restrict__ cnt, const float* __restrict__ Wout,
                        const float* __restrict__ bout, float* __restrict__ out) {
    int g = threadIdx.x;
    if (g >= N_GRAPHS) return;
    float c = fmaxf((float)cnt[g], 1.0f);
    float acc = bout[0];
    for (int ch = 0; ch < EMB; ++ch) {
        acc += ord2f(gmax[g * EMB + ch]) * Wout[ch]
             + (gsum[g * EMB + ch] / c) * Wout[EMB + ch];
    }
    out[g] = acc;
}

extern "C" void kernel_launch(void* const* d_in, const int* in_sizes, int n_in,
                              void* d_out, int out_size, void* d_ws, size_t ws_size,
                              hipStream_t stream) {
    const float* x         = (const float*)d_in[0];
    const int*   edge_idx  = (const int*)d_in[1];
    const float* edge_attr = (const float*)d_in[2];
    const int*   batch     = (const int*)d_in[3];
    const float* W0 = (const float*)d_in[4];
    const float* b0 = (const float*)d_in[5];
    const float* W1 = (const float*)d_in[6];
    const float* b1 = (const float*)d_in[7];
    const float* W2 = (const float*)d_in[8];
    const float* b2 = (const float*)d_in[9];
    const float* W3 = (const float*)d_in[10];
    const float* b3 = (const float*)d_in[11];
    const float* Wout = (const float*)d_in[12];
    const float* bout = (const float*)d_in[13];
    float* out = (float*)d_out;

    const int* src = edge_idx;            // edge_index[0]
    const int* dst = edge_idx + N_EDGES;  // edge_index[1]

    // workspace layout (~33 MB)
    char* ws = (char*)d_ws;
    float*  dinv      = (float*)ws;  ws += (size_t)N_NODES * sizeof(float);   // 200000 B (8B-mult)
    unsigned long long* cnt64 = (unsigned long long*)ws;
    ws += (size_t)N_NODES * CPAD64 * sizeof(unsigned long long);
    int*    row_start = (int*)ws;    ws += (size_t)N_NODES * sizeof(int);
    int*    row_end   = (int*)ws;    ws += (size_t)N_NODES * sizeof(int);
    int*    slot_in   = (int*)ws;    ws += (size_t)N_EDGES * sizeof(int);
    int*    total     = (int*)ws;    ws += 4 * sizeof(int);  // keep 16B alignment
    int2*   csr       = (int2*)ws;   ws += (size_t)N_EDGES * sizeof(int2);
    __half* bufL      = (__half*)ws; ws += (size_t)N_NODES * EMB * sizeof(__half);
    __half* bufH      = (__half*)ws; ws += (size_t)N_NODES * EMB * sizeof(__half);
    int*    gmax      = (int*)ws;    ws += N_GRAPHS * EMB * sizeof(int);
    float*  gsum      = (float*)ws;  ws += N_GRAPHS * EMB * sizeof(float);
    int*    cnt       = (int*)ws;    ws += N_GRAPHS * sizeof(int);

    const int nodeB = (N_NODES + 255) / 256;
    const int edgeB = (N_EDGES + 255) / 256;
    const int waveB = (N_NODES * 64 + 255) / 256;  // one wave per node
    const int gemmB = (N_NODES + 63) / 64;         // 782 blocks, 64-row tiles
    const int initB = (N_NODES * CPAD64 + 255) / 256;

    // CSR precompute (norm fully folded: dinv[src] -> GEMM epilogue, dinv[dst] -> agg;
    // count+weighted-degree collected by ONE packed 64-bit atomic per edge)
    init_k<<<initB, 256, 0, stream>>>(cnt64, total, gmax, gsum, cnt);
    hist_k<<<edgeB, 256, 0, stream>>>(dst, edge_attr, cnt64, slot_in);
    alloc_k<<<nodeB, 256, 0, stream>>>(cnt64, row_start, row_end, total, dinv);
    scatter_k<<<edgeB, 256, 0, stream>>>(src, dst, edge_attr, slot_in, row_start, csr);

    const float* Wl[4] = {W0, W1, W2, W3};
    const float* bl[4] = {b0, b1, b2, b3};
    for (int l = 0; l < 4; ++l) {
        if (l == 0) gemm_k<IN_CH, false><<<gemmB, 256, 0, stream>>>(x, Wl[0], dinv, bufL);
        else        gemm_k<EMB, true>   <<<gemmB, 256, 0, stream>>>(bufH, Wl[l], dinv, bufL);
        fused_agg_k<<<waveB, 256, 0, stream>>>(bufL, csr, row_start, row_end, dinv, bl[l], bufH);
    }

    pool_k<<<(((N_NODES + POOL_CHUNK - 1) / POOL_CHUNK) * 64 + 255) / 256, 256, 0, stream>>>(
        bufH, batch, gmax, gsum, cnt);
    final_k<<<1, 64, 0, stream>>>(gmax, gsum, cnt, Wout, bout, out);
}

// Round 5
// 351.668 us; speedup vs baseline: 1.1807x; 1.0673x over previous
//
#include <hip/hip_runtime.h>
#include <hip/hip_fp16.h>
#include <math.h>
#include <limits.h>

#define N_NODES 50000
#define N_EDGES 800000
#define N_GRAPHS 64
#define IN_CH 128
#define EMB 64
#define POOL_CHUNK 16   // 50000 = 16 * 3125 exactly
#define CPAD64 16       // one 128B line per node: single u64 = (count<<44) | wsum_fx24
#define CNT_SHIFT 44
#define FX_SCALE 16777216.0f   // 2^24 fixed-point for edge weights (w in [0,1))

typedef _Float16 f16;
typedef __attribute__((ext_vector_type(8))) _Float16 half8;
typedef __attribute__((ext_vector_type(4))) float f32x4;

// ---------- init: packed counters=0, total=0, pool accumulators ----------
__global__ void init_k(unsigned long long* cnt64, int* total, int* gmax,
                       float* gsum, int* cnt) {
    int i = blockIdx.x * blockDim.x + threadIdx.x;
    if (i < N_NODES * CPAD64) cnt64[i] = 0ULL;
    if (i == 0) *total = 0;
    if (i < N_GRAPHS * EMB) { gmax[i] = INT_MIN; gsum[i] = 0.f; }
    if (i < N_GRAPHS) cnt[i] = 0;
}

// ---------- histogram: ONE packed 64-bit atomic per edge ----------
// high 20 bits: in-degree count (slot allocation); low 44 bits: sum of w in 2^-24
// fixed point (max realistic sum ~2^30, no overflow into count field).
__global__ void hist_k(const int* __restrict__ dst, const float* __restrict__ w,
                       unsigned long long* cnt64, int* __restrict__ slot_in) {
    int e = blockIdx.x * blockDim.x + threadIdx.x;
    if (e >= N_EDGES) return;
    unsigned long long fx = (unsigned long long)(w[e] * FX_SCALE + 0.5f);
    unsigned long long old = atomicAdd(&cnt64[(size_t)dst[e] * CPAD64],
                                       (1ULL << CNT_SHIFT) | fx);
    slot_in[e] = (int)(old >> CNT_SHIFT);
}

// ---------- CSR range allocation: wave-scan + one atomic per wave; dinv folded ----------
__global__ void alloc_k(const unsigned long long* __restrict__ cnt64,
                        int* __restrict__ row_start, int* __restrict__ row_end,
                        int* total, float* __restrict__ dinv) {
    int i = blockIdx.x * blockDim.x + threadIdx.x;
    int lane = threadIdx.x & 63;
    unsigned long long v = (i < N_NODES) ? cnt64[(size_t)i * CPAD64] : 0ULL;
    int c = (int)(v >> CNT_SHIFT);
    int inc = c;
    for (int off = 1; off < 64; off <<= 1) {
        int t = __shfl_up(inc, off);
        if (lane >= off) inc += t;
    }
    int base;
    if (lane == 63) base = atomicAdd(total, inc);
    base = __shfl(base, 63);
    int excl = base + inc - c;
    if (i < N_NODES) {
        row_start[i] = excl;
        row_end[i] = excl + c;
        float degw = (float)(v & ((1ULL << CNT_SHIFT) - 1)) * (1.0f / FX_SCALE);
        float d = 1.0f + degw;  // + self-loop weight 1
        dinv[i] = d > 0.f ? rsqrtf(d) : 0.f;
    }
}

// ---------- scatter edges into CSR slots (atomic-free) ----------
// csr.x = src * EMB * 2 (BYTE offset into the fp16 feature buffer: kills the
// per-gather 64-bit mad in fused_agg); csr.y = raw w.
__global__ void scatter_k(const int* __restrict__ src, const int* __restrict__ dst,
                          const float* __restrict__ w, const int* __restrict__ slot_in,
                          const int* __restrict__ row_start, int2* __restrict__ csr) {
    int e = blockIdx.x * blockDim.x + threadIdx.x;
    if (e >= N_EDGES) return;
    int d = dst[e];
    int slot = row_start[d] + slot_in[e];
    csr[slot] = make_int2(src[e] * (EMB * 2), __float_as_int(w[e]));
}

// ---------- hs = dinv * (A @ W) via MFMA 16x16x32 f16 ----------
// 64-row block, 4 waves; wave w owns rows 16w..16w+15 x all 64 cols (4 col-tiles).
// Fragment layout (gfx950, guide §3): A row=lane&15, k=8*(lane>>4)+j;
// B col=lane&15 (W staged TRANSPOSED in LDS for contiguous k); 
// C/D col=lane&15, row=4*(lane>>4)+reg  [HW-verified].
template<int K, bool HALF_IN>
__global__ __launch_bounds__(256) void gemm_k(const void* __restrict__ A_,
                                              const float* __restrict__ W,
                                              const float* __restrict__ dinv,
                                              __half* __restrict__ out) {
    constexpr int LDK = K + 8;   // +16B pad: ds_read_b128 2-way bank aliasing (free)
    __shared__ __align__(16) f16 Al[64 * LDK];
    __shared__ __align__(16) f16 Wt[EMB * LDK];   // Wt[n][k]
    int tid = threadIdx.x;
    long rowBase = (long)blockIdx.x * 64;
    int validRows = (int)min((long)64, (long)N_NODES - rowBase);

    if constexpr (HALF_IN) {
        const __half* Ah = (const __half*)A_ + rowBase * K;
        constexpr int CH = K / 8;
        for (int i = tid; i < validRows * CH; i += 256) {
            int r = i / CH, c = i % CH;
            uint4 v = *(const uint4*)(Ah + (long)r * K + c * 8);
            *(uint4*)&Al[r * LDK + c * 8] = v;
        }
    } else {
        const float* Af = (const float*)A_;
        constexpr int CH = K / 4;
        for (int i = tid; i < validRows * CH; i += 256) {
            int r = i / CH, c = i % CH;
            float4 v = *(const float4*)(Af + (rowBase + r) * K + c * 4);
            __half2 p0 = __floats2half2_rn(v.x, v.y);
            __half2 p1 = __floats2half2_rn(v.z, v.w);
            uint2 u = make_uint2(*(unsigned int*)&p0, *(unsigned int*)&p1);
            *(uint2*)&Al[r * LDK + c * 4] = u;
        }
    }
    {   // zero-fill invalid rows (last block only; full blocks skip)
        constexpr int CZ = K / 8;
        for (int i = tid + validRows * CZ; i < 64 * CZ; i += 256) {
            int r = i / CZ, c = i % CZ;
            *(uint4*)&Al[r * LDK + c * 8] = make_uint4(0, 0, 0, 0);
        }
    }
    {   // stage W transposed fp32 -> fp16 (K x 64 -> Wt[64][K])
        const float4* Wg = (const float4*)W;
        for (int i = tid; i < K * (EMB / 4); i += 256) {
            int k = i >> 4, nq = i & 15;   // EMB/4 == 16
            float4 v = Wg[i];
            Wt[(4 * nq + 0) * LDK + k] = (f16)v.x;
            Wt[(4 * nq + 1) * LDK + k] = (f16)v.y;
            Wt[(4 * nq + 2) * LDK + k] = (f16)v.z;
            Wt[(4 * nq + 3) * LDK + k] = (f16)v.w;
        }
    }
    __syncthreads();

    int wv = tid >> 6, lane = tid & 63;
    int l15 = lane & 15, kg = (lane >> 4) * 8;
    const f16* Ap = &Al[(wv * 16 + l15) * LDK + kg];
    const f16* Bp = &Wt[l15 * LDK + kg];
    f32x4 acc0 = {0.f, 0.f, 0.f, 0.f};
    f32x4 acc1 = acc0, acc2 = acc0, acc3 = acc0;
#pragma unroll
    for (int ks = 0; ks < K / 32; ++ks) {
        int k0 = ks * 32;
        half8 a  = *(const half8*)(Ap + k0);
        half8 b0 = *(const half8*)(Bp + k0);
        half8 b1 = *(const half8*)(Bp + 16 * LDK + k0);
        half8 b2 = *(const half8*)(Bp + 32 * LDK + k0);
        half8 b3 = *(const half8*)(Bp + 48 * LDK + k0);
        acc0 = __builtin_amdgcn_mfma_f32_16x16x32_f16(a, b0, acc0, 0, 0, 0);
        acc1 = __builtin_amdgcn_mfma_f32_16x16x32_f16(a, b1, acc1, 0, 0, 0);
        acc2 = __builtin_amdgcn_mfma_f32_16x16x32_f16(a, b2, acc2, 0, 0, 0);
        acc3 = __builtin_amdgcn_mfma_f32_16x16x32_f16(a, b3, acc3, 0, 0, 0);
    }
    int orow = wv * 16 + (lane >> 4) * 4;
#pragma unroll
    for (int i = 0; i < 4; ++i) {
        long row = rowBase + orow + i;
        if (row >= N_NODES) break;
        float dv = dinv[row];
        __half* op = &out[row * EMB + l15];
        op[0]  = __float2half(dv * acc0[i]);
        op[16] = __float2half(dv * acc1[i]);
        op[32] = __float2half(dv * acc2[i]);
        op[48] = __float2half(dv * acc3[i]);
    }
}

// ---------- fused aggregation: self-loop + bias + CSR gather + tanh ----------
// one wave per node; lane = channel; 8 gathers in flight. hs rows fp16 (2 lines/
// edge); csr.x is a BYTE offset (addressing = one 32-bit add per gather);
// out = tanh(dinv*(hs_self + sum w*hs_src) + b), fp16.
__global__ __launch_bounds__(256) void fused_agg_k(const __half* __restrict__ hs,
                                                   const int2* __restrict__ csr,
                                                   const int* __restrict__ row_start,
                                                   const int* __restrict__ row_end,
                                                   const float* __restrict__ dinv,
                                                   const float* __restrict__ b,
                                                   __half* __restrict__ out) {
    int node = (blockIdx.x * blockDim.x + threadIdx.x) >> 6;
    int lane = threadIdx.x & 63;
    if (node >= N_NODES) return;
    const char* hsb = (const char*)hs + (size_t)(lane * 2);
    float di = dinv[node];
    float acc = __half2float(hs[(long)node * EMB + lane]);   // self term
    int e = row_start[node];
    int end = row_end[node];
    for (; e + 7 < end; e += 8) {
        int2 r[8];
        __half v[8];
#pragma unroll
        for (int i = 0; i < 8; ++i) r[i] = csr[e + i];
#pragma unroll
        for (int i = 0; i < 8; ++i) v[i] = *(const __half*)(hsb + (unsigned)r[i].x);
#pragma unroll
        for (int i = 0; i < 8; ++i) acc += __int_as_float(r[i].y) * __half2float(v[i]);
    }
    for (; e + 3 < end; e += 4) {
        int2 r0 = csr[e], r1 = csr[e + 1], r2 = csr[e + 2], r3 = csr[e + 3];
        float v0 = __half2float(*(const __half*)(hsb + (unsigned)r0.x));
        float v1 = __half2float(*(const __half*)(hsb + (unsigned)r1.x));
        float v2 = __half2float(*(const __half*)(hsb + (unsigned)r2.x));
        float v3 = __half2float(*(const __half*)(hsb + (unsigned)r3.x));
        acc += __int_as_float(r0.y) * v0;
        acc += __int_as_float(r1.y) * v1;
        acc += __int_as_float(r2.y) * v2;
        acc += __int_as_float(r3.y) * v3;
    }
    for (; e < end; ++e) {
        int2 r0 = csr[e];
        acc += __int_as_float(r0.y) * __half2float(*(const __half*)(hsb + (unsigned)r0.x));
    }
    float o = tanhf(di * acc + b[lane]);
    __half oh = __float2half(o);
    __builtin_nontemporal_store(*(unsigned short*)&oh,
                                (unsigned short*)&out[(long)node * EMB + lane]);
}

// ---------- pooling ----------
__device__ inline int f2ord(float x) {
    int bb = __float_as_int(x);
    return bb >= 0 ? bb : (bb ^ 0x7fffffff);
}
__device__ inline float ord2f(int k) {
    return __int_as_float(k >= 0 ? k : (k ^ 0x7fffffff));
}

// wave = 16 contiguous nodes (batch sorted); lane = channel.
__global__ __launch_bounds__(256) void pool_k(const __half* __restrict__ h,
                                              const int* __restrict__ batch,
                                              int* gmax, float* gsum, int* cnt) {
    int wave = (blockIdx.x * blockDim.x + threadIdx.x) >> 6;
    int lane = threadIdx.x & 63;
    int start = wave * POOL_CHUNK;
    if (start >= N_NODES) return;   // 50000 % 16 == 0 -> full chunks always
    int bsel = (lane < POOL_CHUNK) ? batch[start + lane] : 0;
    float v[POOL_CHUNK];
#pragma unroll
    for (int i = 0; i < POOL_CHUNK; ++i)
        v[i] = __half2float(h[(long)(start + i) * EMB + lane]);
    int curg = __shfl(bsel, 0);
    float mx = -INFINITY, sm = 0.f;
    int ct = 0;
#pragma unroll
    for (int i = 0; i < POOL_CHUNK; ++i) {
        int g = __shfl(bsel, i);
        if (g != curg) {
            atomicMax(&gmax[curg * EMB + lane], f2ord(mx));
            atomicAdd(&gsum[curg * EMB + lane], sm);
            if (lane == 0) atomicAdd(&cnt[curg], ct);
            curg = g; mx = -INFINITY; sm = 0.f; ct = 0;
        }
        mx = fmaxf(mx, v[i]);
        sm += v[i];
        ++ct;
    }
    atomicMax(&gmax[curg * EMB + lane], f2ord(mx));
    atomicAdd(&gsum[curg * EMB + lane], sm);
    if (lane == 0) atomicAdd(&cnt[curg], ct);
}

__global__ void final_k(const int* __restrict__ gmax, const float* __restrict__ gsum,
                        const int* __restrict__ cnt, const float* __restrict__ Wout,
                        const float* __restrict__ bout, float* __restrict__ out) {
    int g = threadIdx.x;
    if (g >= N_GRAPHS) return;
    float c = fmaxf((float)cnt[g], 1.0f);
    float acc = bout[0];
    for (int ch = 0; ch < EMB; ++ch) {
        acc += ord2f(gmax[g * EMB + ch]) * Wout[ch]
             + (gsum[g * EMB + ch] / c) * Wout[EMB + ch];
    }
    out[g] = acc;
}

extern "C" void kernel_launch(void* const* d_in, const int* in_sizes, int n_in,
                              void* d_out, int out_size, void* d_ws, size_t ws_size,
                              hipStream_t stream) {
    const float* x         = (const float*)d_in[0];
    const int*   edge_idx  = (const int*)d_in[1];
    const float* edge_attr = (const float*)d_in[2];
    const int*   batch     = (const int*)d_in[3];
    const float* W0 = (const float*)d_in[4];
    const float* b0 = (const float*)d_in[5];
    const float* W1 = (const float*)d_in[6];
    const float* b1 = (const float*)d_in[7];
    const float* W2 = (const float*)d_in[8];
    const float* b2 = (const float*)d_in[9];
    const float* W3 = (const float*)d_in[10];
    const float* b3 = (const float*)d_in[11];
    const float* Wout = (const float*)d_in[12];
    const float* bout = (const float*)d_in[13];
    float* out = (float*)d_out;

    const int* src = edge_idx;            // edge_index[0]
    const int* dst = edge_idx + N_EDGES;  // edge_index[1]

    // workspace layout (~33 MB)
    char* ws = (char*)d_ws;
    float*  dinv      = (float*)ws;  ws += (size_t)N_NODES * sizeof(float);
    unsigned long long* cnt64 = (unsigned long long*)ws;
    ws += (size_t)N_NODES * CPAD64 * sizeof(unsigned long long);
    int*    row_start = (int*)ws;    ws += (size_t)N_NODES * sizeof(int);
    int*    row_end   = (int*)ws;    ws += (size_t)N_NODES * sizeof(int);
    int*    slot_in   = (int*)ws;    ws += (size_t)N_EDGES * sizeof(int);
    int*    total     = (int*)ws;    ws += 4 * sizeof(int);  // keep 16B alignment
    int2*   csr       = (int2*)ws;   ws += (size_t)N_EDGES * sizeof(int2);
    __half* bufL      = (__half*)ws; ws += (size_t)N_NODES * EMB * sizeof(__half);
    __half* bufH      = (__half*)ws; ws += (size_t)N_NODES * EMB * sizeof(__half);
    int*    gmax      = (int*)ws;    ws += N_GRAPHS * EMB * sizeof(int);
    float*  gsum      = (float*)ws;  ws += N_GRAPHS * EMB * sizeof(float);
    int*    cnt       = (int*)ws;    ws += N_GRAPHS * sizeof(int);

    const int nodeB = (N_NODES + 255) / 256;
    const int edgeB = (N_EDGES + 255) / 256;
    const int waveB = (N_NODES * 64 + 255) / 256;  // one wave per node
    const int gemmB = (N_NODES + 63) / 64;         // 782 blocks, 64-row tiles
    const int initB = (N_NODES * CPAD64 + 255) / 256;

    // CSR precompute (norm fully folded; count+weighted-degree via ONE 64b atomic)
    init_k<<<initB, 256, 0, stream>>>(cnt64, total, gmax, gsum, cnt);
    hist_k<<<edgeB, 256, 0, stream>>>(dst, edge_attr, cnt64, slot_in);
    alloc_k<<<nodeB, 256, 0, stream>>>(cnt64, row_start, row_end, total, dinv);
    scatter_k<<<edgeB, 256, 0, stream>>>(src, dst, edge_attr, slot_in, row_start, csr);

    const float* Wl[4] = {W0, W1, W2, W3};
    const float* bl[4] = {b0, b1, b2, b3};
    for (int l = 0; l < 4; ++l) {
        if (l == 0) gemm_k<IN_CH, false><<<gemmB, 256, 0, stream>>>(x, Wl[0], dinv, bufL);
        else        gemm_k<EMB, true>   <<<gemmB, 256, 0, stream>>>(bufH, Wl[l], dinv, bufL);
        fused_agg_k<<<waveB, 256, 0, stream>>>(bufL, csr, row_start, row_end, dinv, bl[l], bufH);
    }

    pool_k<<<(((N_NODES + POOL_CHUNK - 1) / POOL_CHUNK) * 64 + 255) / 256, 256, 0, stream>>>(
        bufH, batch, gmax, gsum, cnt);
    final_k<<<1, 64, 0, stream>>>(gmax, gsum, cnt, Wout, bout, out);
}

// Round 7
// 342.964 us; speedup vs baseline: 1.2107x; 1.0254x over previous
//
#include <hip/hip_runtime.h>
#include <hip/hip_fp16.h>
#include <math.h>
#include <limits.h>

#define N_NODES 50000
#define N_EDGES 800000
#define N_GRAPHS 64
#define IN_CH 128
#define EMB 64
#define POOL_CHUNK 16   // 50000 = 16 * 3125 exactly
#define CPAD64 16       // one 128B line per node: single u64 = (count<<44) | wsum_fx24
#define CNT_SHIFT 44
#define FX_SCALE 16777216.0f   // 2^24 fixed-point for edge weights (w in [0,1))

typedef _Float16 f16;
typedef __attribute__((ext_vector_type(8))) _Float16 half8;
typedef __attribute__((ext_vector_type(4))) float f32x4;

// ---------- init: packed counters=0, total=0, pool accumulators ----------
__global__ void init_k(unsigned long long* cnt64, int* total, int* gmax,
                       float* gsum, int* cnt) {
    int i = blockIdx.x * blockDim.x + threadIdx.x;
    if (i < N_NODES * CPAD64) cnt64[i] = 0ULL;
    if (i == 0) *total = 0;
    if (i < N_GRAPHS * EMB) { gmax[i] = INT_MIN; gsum[i] = 0.f; }
    if (i < N_GRAPHS) cnt[i] = 0;
}

// ---------- histogram: ONE packed 64-bit atomic per edge ----------
// high 20 bits: in-degree count (slot allocation); low 44 bits: sum of w in 2^-24
// fixed point (max realistic sum ~2^30, no overflow into count field).
__global__ void hist_k(const int* __restrict__ dst, const float* __restrict__ w,
                       unsigned long long* cnt64, int* __restrict__ slot_in) {
    int e = blockIdx.x * blockDim.x + threadIdx.x;
    if (e >= N_EDGES) return;
    unsigned long long fx = (unsigned long long)(w[e] * FX_SCALE + 0.5f);
    unsigned long long old = atomicAdd(&cnt64[(size_t)dst[e] * CPAD64],
                                       (1ULL << CNT_SHIFT) | fx);
    slot_in[e] = (int)(old >> CNT_SHIFT);
}

// ---------- CSR range allocation: wave-scan + one atomic per wave; dinv folded ----------
__global__ void alloc_k(const unsigned long long* __restrict__ cnt64,
                        int* __restrict__ row_start, int* __restrict__ row_end,
                        int* total, float* __restrict__ dinv) {
    int i = blockIdx.x * blockDim.x + threadIdx.x;
    int lane = threadIdx.x & 63;
    unsigned long long v = (i < N_NODES) ? cnt64[(size_t)i * CPAD64] : 0ULL;
    int c = (int)(v >> CNT_SHIFT);
    int inc = c;
    for (int off = 1; off < 64; off <<= 1) {
        int t = __shfl_up(inc, off);
        if (lane >= off) inc += t;
    }
    int base;
    if (lane == 63) base = atomicAdd(total, inc);
    base = __shfl(base, 63);
    int excl = base + inc - c;
    if (i < N_NODES) {
        row_start[i] = excl;
        row_end[i] = excl + c;
        float degw = (float)(v & ((1ULL << CNT_SHIFT) - 1)) * (1.0f / FX_SCALE);
        float d = 1.0f + degw;  // + self-loop weight 1
        dinv[i] = d > 0.f ? rsqrtf(d) : 0.f;
    }
}

// ---------- scatter edges into CSR slots (atomic-free) ----------
// csr.x = src * EMB * 2 (BYTE offset into the fp16 feature buffer); csr.y = raw w.
__global__ void scatter_k(const int* __restrict__ src, const int* __restrict__ dst,
                          const float* __restrict__ w, const int* __restrict__ slot_in,
                          const int* __restrict__ row_start, int2* __restrict__ csr) {
    int e = blockIdx.x * blockDim.x + threadIdx.x;
    if (e >= N_EDGES) return;
    int d = dst[e];
    int slot = row_start[d] + slot_in[e];
    csr[slot] = make_int2(src[e] * (EMB * 2), __float_as_int(w[e]));
}

// ---------- hs = dinv * (A @ W) via MFMA 16x16x32 f16 ----------
// 64-row block, 4 waves; wave w owns rows 16w..16w+15 x all 64 cols (4 col-tiles).
// Fragment layout (gfx950, guide §3): A row=lane&15, k=8*(lane>>4)+j;
// B col=lane&15 (W staged TRANSPOSED in LDS); C/D col=lane&15, row=4*(lane>>4)+reg.
template<int K, bool HALF_IN>
__global__ __launch_bounds__(256) void gemm_k(const void* __restrict__ A_,
                                              const float* __restrict__ W,
                                              const float* __restrict__ dinv,
                                              __half* __restrict__ out) {
    constexpr int LDK = K + 8;   // +16B pad: ds_read_b128 2-way bank aliasing (free)
    __shared__ __align__(16) f16 Al[64 * LDK];
    __shared__ __align__(16) f16 Wt[EMB * LDK];   // Wt[n][k]
    int tid = threadIdx.x;
    long rowBase = (long)blockIdx.x * 64;
    int validRows = (int)min((long)64, (long)N_NODES - rowBase);

    if constexpr (HALF_IN) {
        const __half* Ah = (const __half*)A_ + rowBase * K;
        constexpr int CH = K / 8;
        for (int i = tid; i < validRows * CH; i += 256) {
            int r = i / CH, c = i % CH;
            uint4 v = *(const uint4*)(Ah + (long)r * K + c * 8);
            *(uint4*)&Al[r * LDK + c * 8] = v;
        }
    } else {
        const float* Af = (const float*)A_;
        constexpr int CH = K / 4;
        for (int i = tid; i < validRows * CH; i += 256) {
            int r = i / CH, c = i % CH;
            float4 v = *(const float4*)(Af + (rowBase + r) * K + c * 4);
            __half2 p0 = __floats2half2_rn(v.x, v.y);
            __half2 p1 = __floats2half2_rn(v.z, v.w);
            uint2 u = make_uint2(*(unsigned int*)&p0, *(unsigned int*)&p1);
            *(uint2*)&Al[r * LDK + c * 4] = u;
        }
    }
    {   // zero-fill invalid rows (last block only; full blocks skip)
        constexpr int CZ = K / 8;
        for (int i = tid + validRows * CZ; i < 64 * CZ; i += 256) {
            int r = i / CZ, c = i % CZ;
            *(uint4*)&Al[r * LDK + c * 8] = make_uint4(0, 0, 0, 0);
        }
    }
    {   // stage W transposed fp32 -> fp16 (K x 64 -> Wt[64][K])
        const float4* Wg = (const float4*)W;
        for (int i = tid; i < K * (EMB / 4); i += 256) {
            int k = i >> 4, nq = i & 15;   // EMB/4 == 16
            float4 v = Wg[i];
            Wt[(4 * nq + 0) * LDK + k] = (f16)v.x;
            Wt[(4 * nq + 1) * LDK + k] = (f16)v.y;
            Wt[(4 * nq + 2) * LDK + k] = (f16)v.z;
            Wt[(4 * nq + 3) * LDK + k] = (f16)v.w;
        }
    }
    __syncthreads();

    int wv = tid >> 6, lane = tid & 63;
    int l15 = lane & 15, kg = (lane >> 4) * 8;
    const f16* Ap = &Al[(wv * 16 + l15) * LDK + kg];
    const f16* Bp = &Wt[l15 * LDK + kg];
    f32x4 acc0 = {0.f, 0.f, 0.f, 0.f};
    f32x4 acc1 = acc0, acc2 = acc0, acc3 = acc0;
#pragma unroll
    for (int ks = 0; ks < K / 32; ++ks) {
        int k0 = ks * 32;
        half8 a  = *(const half8*)(Ap + k0);
        half8 b0 = *(const half8*)(Bp + k0);
        half8 b1 = *(const half8*)(Bp + 16 * LDK + k0);
        half8 b2 = *(const half8*)(Bp + 32 * LDK + k0);
        half8 b3 = *(const half8*)(Bp + 48 * LDK + k0);
        acc0 = __builtin_amdgcn_mfma_f32_16x16x32_f16(a, b0, acc0, 0, 0, 0);
        acc1 = __builtin_amdgcn_mfma_f32_16x16x32_f16(a, b1, acc1, 0, 0, 0);
        acc2 = __builtin_amdgcn_mfma_f32_16x16x32_f16(a, b2, acc2, 0, 0, 0);
        acc3 = __builtin_amdgcn_mfma_f32_16x16x32_f16(a, b3, acc3, 0, 0, 0);
    }
    int orow = wv * 16 + (lane >> 4) * 4;
#pragma unroll
    for (int i = 0; i < 4; ++i) {
        long row = rowBase + orow + i;
        if (row >= N_NODES) break;
        float dv = dinv[row];
        __half* op = &out[row * EMB + l15];
        op[0]  = __float2half(dv * acc0[i]);
        op[16] = __float2half(dv * acc1[i]);
        op[32] = __float2half(dv * acc2[i]);
        op[48] = __float2half(dv * acc3[i]);
    }
}

// ---------- fused aggregation: self-loop + bias + CSR gather + tanh ----------
// one wave per node; lane = channel; 8 gathers in flight.
// csr is read with ONE lane-spread load per 8-edge batch (csr[e+(lane&7)]: one
// 64B line, one instruction) and broadcast via v_readlane -> (src,w) live in
// SGPRs. This removes 8 redundant broadcast-load line-requests per batch
// (line-requests/edge 3 -> 2.125) and turns gather addressing into
// scalar-base + constant voffset. Gather structure (8 in flight) unchanged.
__global__ __launch_bounds__(256) void fused_agg_k(const __half* __restrict__ hs,
                                                   const int2* __restrict__ csr,
                                                   const int* __restrict__ row_start,
                                                   const int* __restrict__ row_end,
                                                   const float* __restrict__ dinv,
                                                   const float* __restrict__ b,
                                                   __half* __restrict__ out) {
    int node = (blockIdx.x * blockDim.x + threadIdx.x) >> 6;
    int lane = threadIdx.x & 63;
    if (node >= N_NODES) return;
    const char* hsb = (const char*)hs + (size_t)(lane * 2);
    float di = dinv[node];
    float acc = __half2float(hs[(long)node * EMB + lane]);   // self term
    int e = row_start[node];
    int end = row_end[node];
    for (; e + 7 < end; e += 8) {
        int2 rl = csr[e + (lane & 7)];   // one 64B line; 8-lane groups identical
        int so[8], wb[8];
#pragma unroll
        for (int i = 0; i < 8; ++i) {
            so[i] = __builtin_amdgcn_readlane(rl.x, i);   // uniform -> SGPR
            wb[i] = __builtin_amdgcn_readlane(rl.y, i);
        }
        __half v[8];
#pragma unroll
        for (int i = 0; i < 8; ++i) v[i] = *(const __half*)(hsb + (unsigned)so[i]);
#pragma unroll
        for (int i = 0; i < 8; ++i) acc += __int_as_float(wb[i]) * __half2float(v[i]);
    }
    for (; e + 3 < end; e += 4) {
        int2 r0 = csr[e], r1 = csr[e + 1], r2 = csr[e + 2], r3 = csr[e + 3];
        float v0 = __half2float(*(const __half*)(hsb + (unsigned)r0.x));
        float v1 = __half2float(*(const __half*)(hsb + (unsigned)r1.x));
        float v2 = __half2float(*(const __half*)(hsb + (unsigned)r2.x));
        float v3 = __half2float(*(const __half*)(hsb + (unsigned)r3.x));
        acc += __int_as_float(r0.y) * v0;
        acc += __int_as_float(r1.y) * v1;
        acc += __int_as_float(r2.y) * v2;
        acc += __int_as_float(r3.y) * v3;
    }
    for (; e < end; ++e) {
        int2 r0 = csr[e];
        acc += __int_as_float(r0.y) * __half2float(*(const __half*)(hsb + (unsigned)r0.x));
    }
    float o = tanhf(di * acc + b[lane]);
    __half oh = __float2half(o);
    __builtin_nontemporal_store(*(unsigned short*)&oh,
                                (unsigned short*)&out[(long)node * EMB + lane]);
}

// ---------- pooling ----------
__device__ inline int f2ord(float x) {
    int bb = __float_as_int(x);
    return bb >= 0 ? bb : (bb ^ 0x7fffffff);
}
__device__ inline float ord2f(int k) {
    return __int_as_float(k >= 0 ? k : (k ^ 0x7fffffff));
}

// wave = 16 contiguous nodes (batch sorted); lane = channel.
__global__ __launch_bounds__(256) void pool_k(const __half* __restrict__ h,
                                              const int* __restrict__ batch,
                                              int* gmax, float* gsum, int* cnt) {
    int wave = (blockIdx.x * blockDim.x + threadIdx.x) >> 6;
    int lane = threadIdx.x & 63;
    int start = wave * POOL_CHUNK;
    if (start >= N_NODES) return;   // 50000 % 16 == 0 -> full chunks always
    int bsel = (lane < POOL_CHUNK) ? batch[start + lane] : 0;
    float v[POOL_CHUNK];
#pragma unroll
    for (int i = 0; i < POOL_CHUNK; ++i)
        v[i] = __half2float(h[(long)(start + i) * EMB + lane]);
    int curg = __shfl(bsel, 0);
    float mx = -INFINITY, sm = 0.f;
    int ct = 0;
#pragma unroll
    for (int i = 0; i < POOL_CHUNK; ++i) {
        int g = __shfl(bsel, i);
        if (g != curg) {
            atomicMax(&gmax[curg * EMB + lane], f2ord(mx));
            atomicAdd(&gsum[curg * EMB + lane], sm);
            if (lane == 0) atomicAdd(&cnt[curg], ct);
            curg = g; mx = -INFINITY; sm = 0.f; ct = 0;
        }
        mx = fmaxf(mx, v[i]);
        sm += v[i];
        ++ct;
    }
    atomicMax(&gmax[curg * EMB + lane], f2ord(mx));
    atomicAdd(&gsum[curg * EMB + lane], sm);
    if (lane == 0) atomicAdd(&cnt[curg], ct);
}

__global__ void final_k(const int* __restrict__ gmax, const float* __restrict__ gsum,
                        const int* __restrict__ cnt, const float* __restrict__ Wout,
                        const float* __restrict__ bout, float* __restrict__ out) {
    int g = threadIdx.x;
    if (g >= N_GRAPHS) return;
    float c = fmaxf((float)cnt[g], 1.0f);
    float acc = bout[0];
    for (int ch = 0; ch < EMB; ++ch) {
        acc += ord2f(gmax[g * EMB + ch]) * Wout[ch]
             + (gsum[g * EMB + ch] / c) * Wout[EMB + ch];
    }
    out[g] = acc;
}

extern "C" void kernel_launch(void* const* d_in, const int* in_sizes, int n_in,
                              void* d_out, int out_size, void* d_ws, size_t ws_size,
                              hipStream_t stream) {
    const float* x         = (const float*)d_in[0];
    const int*   edge_idx  = (const int*)d_in[1];
    const float* edge_attr = (const float*)d_in[2];
    const int*   batch     = (const int*)d_in[3];
    const float* W0 = (const float*)d_in[4];
    const float* b0 = (const float*)d_in[5];
    const float* W1 = (const float*)d_in[6];
    const float* b1 = (const float*)d_in[7];
    const float* W2 = (const float*)d_in[8];
    const float* b2 = (const float*)d_in[9];
    const float* W3 = (const float*)d_in[10];
    const float* b3 = (const float*)d_in[11];
    const float* Wout = (const float*)d_in[12];
    const float* bout = (const float*)d_in[13];
    float* out = (float*)d_out;

    const int* src = edge_idx;            // edge_index[0]
    const int* dst = edge_idx + N_EDGES;  // edge_index[1]

    // workspace layout (~33 MB)
    char* ws = (char*)d_ws;
    float*  dinv      = (float*)ws;  ws += (size_t)N_NODES * sizeof(float);
    unsigned long long* cnt64 = (unsigned long long*)ws;
    ws += (size_t)N_NODES * CPAD64 * sizeof(unsigned long long);
    int*    row_start = (int*)ws;    ws += (size_t)N_NODES * sizeof(int);
    int*    row_end   = (int*)ws;    ws += (size_t)N_NODES * sizeof(int);
    int*    slot_in   = (int*)ws;    ws += (size_t)N_EDGES * sizeof(int);
    int*    total     = (int*)ws;    ws += 4 * sizeof(int);  // keep 16B alignment
    int2*   csr       = (int2*)ws;   ws += (size_t)N_EDGES * sizeof(int2);
    __half* bufL      = (__half*)ws; ws += (size_t)N_NODES * EMB * sizeof(__half);
    __half* bufH      = (__half*)ws; ws += (size_t)N_NODES * EMB * sizeof(__half);
    int*    gmax      = (int*)ws;    ws += N_GRAPHS * EMB * sizeof(int);
    float*  gsum      = (float*)ws;  ws += N_GRAPHS * EMB * sizeof(float);
    int*    cnt       = (int*)ws;    ws += N_GRAPHS * sizeof(int);

    const int nodeB = (N_NODES + 255) / 256;
    const int edgeB = (N_EDGES + 255) / 256;
    const int waveB = (N_NODES * 64 + 255) / 256;  // one wave per node
    const int gemmB = (N_NODES + 63) / 64;         // 782 blocks, 64-row tiles
    const int initB = (N_NODES * CPAD64 + 255) / 256;

    // CSR precompute (norm fully folded; count+weighted-degree via ONE 64b atomic)
    init_k<<<initB, 256, 0, stream>>>(cnt64, total, gmax, gsum, cnt);
    hist_k<<<edgeB, 256, 0, stream>>>(dst, edge_attr, cnt64, slot_in);
    alloc_k<<<nodeB, 256, 0, stream>>>(cnt64, row_start, row_end, total, dinv);
    scatter_k<<<edgeB, 256, 0, stream>>>(src, dst, edge_attr, slot_in, row_start, csr);

    const float* Wl[4] = {W0, W1, W2, W3};
    const float* bl[4] = {b0, b1, b2, b3};
    for (int l = 0; l < 4; ++l) {
        if (l == 0) gemm_k<IN_CH, false><<<gemmB, 256, 0, stream>>>(x, Wl[0], dinv, bufL);
        else        gemm_k<EMB, true>   <<<gemmB, 256, 0, stream>>>(bufH, Wl[l], dinv, bufL);
        fused_agg_k<<<waveB, 256, 0, stream>>>(bufL, csr, row_start, row_end, dinv, bl[l], bufH);
    }

    pool_k<<<(((N_NODES + POOL_CHUNK - 1) / POOL_CHUNK) * 64 + 255) / 256, 256, 0, stream>>>(
        bufH, batch, gmax, gsum, cnt);
    final_k<<<1, 64, 0, stream>>>(gmax, gsum, cnt, Wout, bout, out);
}

// Round 8
// 319.337 us; speedup vs baseline: 1.3003x; 1.0740x over previous
//
#include <hip/hip_runtime.h>
#include <hip/hip_fp16.h>
#include <math.h>
#include <limits.h>

#define N_NODES 50000
#define N_EDGES 800000
#define N_GRAPHS 64
#define IN_CH 128
#define EMB 64
#define POOL_CHUNK 16   // 50000 = 16 * 3125 exactly
#define CPAD64 16       // one 128B line per node: single u64 = (count<<44) | wsum_fx24
#define CNT_SHIFT 44
#define FX_SCALE 16777216.0f   // 2^24 fixed-point for edge weights (w in [0,1))

typedef _Float16 f16;
typedef __attribute__((ext_vector_type(8))) _Float16 half8;
typedef __attribute__((ext_vector_type(4))) float f32x4;

// ---------- init: packed counters=0, total=0, pool accumulators ----------
__global__ void init_k(unsigned long long* cnt64, int* total, int* gmax,
                       float* gsum, int* cnt) {
    int i = blockIdx.x * blockDim.x + threadIdx.x;
    if (i < N_NODES * CPAD64) cnt64[i] = 0ULL;
    if (i == 0) *total = 0;
    if (i < N_GRAPHS * EMB) { gmax[i] = INT_MIN; gsum[i] = 0.f; }
    if (i < N_GRAPHS) cnt[i] = 0;
}

// ---------- histogram: ONE packed 64-bit atomic per edge ----------
__global__ void hist_k(const int* __restrict__ dst, const float* __restrict__ w,
                       unsigned long long* cnt64, int* __restrict__ slot_in) {
    int e = blockIdx.x * blockDim.x + threadIdx.x;
    if (e >= N_EDGES) return;
    unsigned long long fx = (unsigned long long)(w[e] * FX_SCALE + 0.5f);
    unsigned long long old = atomicAdd(&cnt64[(size_t)dst[e] * CPAD64],
                                       (1ULL << CNT_SHIFT) | fx);
    slot_in[e] = (int)(old >> CNT_SHIFT);
}

// ---------- CSR range allocation: wave-scan + one atomic per wave; dinv folded ----------
__global__ void alloc_k(const unsigned long long* __restrict__ cnt64,
                        int* __restrict__ row_start, int* __restrict__ row_end,
                        int* total, float* __restrict__ dinv) {
    int i = blockIdx.x * blockDim.x + threadIdx.x;
    int lane = threadIdx.x & 63;
    unsigned long long v = (i < N_NODES) ? cnt64[(size_t)i * CPAD64] : 0ULL;
    int c = (int)(v >> CNT_SHIFT);
    int inc = c;
    for (int off = 1; off < 64; off <<= 1) {
        int t = __shfl_up(inc, off);
        if (lane >= off) inc += t;
    }
    int base;
    if (lane == 63) base = atomicAdd(total, inc);
    base = __shfl(base, 63);
    int excl = base + inc - c;
    if (i < N_NODES) {
        row_start[i] = excl;
        row_end[i] = excl + c;
        float degw = (float)(v & ((1ULL << CNT_SHIFT) - 1)) * (1.0f / FX_SCALE);
        float d = 1.0f + degw;  // + self-loop weight 1
        dinv[i] = d > 0.f ? rsqrtf(d) : 0.f;
    }
}

// ---------- scatter edges into CSR slots (atomic-free) ----------
// csr.x = src * EMB * 2 (BYTE offset into fp16 feature buffer); csr.y = raw w.
__global__ void scatter_k(const int* __restrict__ src, const int* __restrict__ dst,
                          const float* __restrict__ w, const int* __restrict__ slot_in,
                          const int* __restrict__ row_start, int2* __restrict__ csr) {
    int e = blockIdx.x * blockDim.x + threadIdx.x;
    if (e >= N_EDGES) return;
    int d = dst[e];
    int slot = row_start[d] + slot_in[e];
    csr[slot] = make_int2(src[e] * (EMB * 2), __float_as_int(w[e]));
}

// ---------- shared agg inner: acc += sum over CSR row (lane = channel) ----------
// 8-edge batches: one lane-spread csr load (64B line) + readlane -> SGPR (src,w);
// tail = one clamped lane-spread batch with uniform-scalar guard.
__device__ inline float agg_row(const char* hsb, const int2* __restrict__ csr,
                                int e, int end, float acc) {
    for (; e + 7 < end; e += 8) {
        int2 rl = csr[e + (threadIdx.x & 7)];
        int so[8], wb[8];
#pragma unroll
        for (int j = 0; j < 8; ++j) {
            so[j] = __builtin_amdgcn_readlane(rl.x, j);
            wb[j] = __builtin_amdgcn_readlane(rl.y, j);
        }
        __half v[8];
#pragma unroll
        for (int j = 0; j < 8; ++j) v[j] = *(const __half*)(hsb + (unsigned)so[j]);
#pragma unroll
        for (int j = 0; j < 8; ++j) acc += __int_as_float(wb[j]) * __half2float(v[j]);
    }
    int n = end - e;   // 0..7, uniform per node
    if (n > 0) {
        int idx = e + (threadIdx.x & 7);
        if (idx >= end) idx = end - 1;
        int2 rl = csr[idx];
#pragma unroll
        for (int j = 0; j < 8; ++j) {
            if (j < n) {
                int so = __builtin_amdgcn_readlane(rl.x, j);
                int wb = __builtin_amdgcn_readlane(rl.y, j);
                acc += __int_as_float(wb) * __half2float(*(const __half*)(hsb + (unsigned)so));
            }
        }
    }
    return acc;
}

// ---------- hs = dinv * (A @ W) via MFMA 16x16x32 f16 (layer 0 only, fp32 input) ----------
template<int K, bool HALF_IN>
__global__ __launch_bounds__(256) void gemm_k(const void* __restrict__ A_,
                                              const float* __restrict__ W,
                                              const float* __restrict__ dinv,
                                              __half* __restrict__ out) {
    constexpr int LDK = K + 8;
    __shared__ __align__(16) f16 Al[64 * LDK];
    __shared__ __align__(16) f16 Wt[EMB * LDK];   // Wt[n][k]
    int tid = threadIdx.x;
    long rowBase = (long)blockIdx.x * 64;
    int validRows = (int)min((long)64, (long)N_NODES - rowBase);

    if constexpr (HALF_IN) {
        const __half* Ah = (const __half*)A_ + rowBase * K;
        constexpr int CH = K / 8;
        for (int i = tid; i < validRows * CH; i += 256) {
            int r = i / CH, c = i % CH;
            uint4 v = *(const uint4*)(Ah + (long)r * K + c * 8);
            *(uint4*)&Al[r * LDK + c * 8] = v;
        }
    } else {
        const float* Af = (const float*)A_;
        constexpr int CH = K / 4;
        for (int i = tid; i < validRows * CH; i += 256) {
            int r = i / CH, c = i % CH;
            float4 v = *(const float4*)(Af + (rowBase + r) * K + c * 4);
            __half2 p0 = __floats2half2_rn(v.x, v.y);
            __half2 p1 = __floats2half2_rn(v.z, v.w);
            uint2 u = make_uint2(*(unsigned int*)&p0, *(unsigned int*)&p1);
            *(uint2*)&Al[r * LDK + c * 4] = u;
        }
    }
    {   // zero-fill invalid rows (last block only)
        constexpr int CZ = K / 8;
        for (int i = tid + validRows * CZ; i < 64 * CZ; i += 256) {
            int r = i / CZ, c = i % CZ;
            *(uint4*)&Al[r * LDK + c * 8] = make_uint4(0, 0, 0, 0);
        }
    }
    {   // stage W transposed fp32 -> fp16
        const float4* Wg = (const float4*)W;
        for (int i = tid; i < K * (EMB / 4); i += 256) {
            int k = i >> 4, nq = i & 15;
            float4 v = Wg[i];
            Wt[(4 * nq + 0) * LDK + k] = (f16)v.x;
            Wt[(4 * nq + 1) * LDK + k] = (f16)v.y;
            Wt[(4 * nq + 2) * LDK + k] = (f16)v.z;
            Wt[(4 * nq + 3) * LDK + k] = (f16)v.w;
        }
    }
    __syncthreads();

    int wv = tid >> 6, lane = tid & 63;
    int l15 = lane & 15, kg = (lane >> 4) * 8;
    const f16* Ap = &Al[(wv * 16 + l15) * LDK + kg];
    const f16* Bp = &Wt[l15 * LDK + kg];
    f32x4 acc0 = {0.f, 0.f, 0.f, 0.f};
    f32x4 acc1 = acc0, acc2 = acc0, acc3 = acc0;
#pragma unroll
    for (int ks = 0; ks < K / 32; ++ks) {
        int k0 = ks * 32;
        half8 a  = *(const half8*)(Ap + k0);
        half8 b0 = *(const half8*)(Bp + k0);
        half8 b1 = *(const half8*)(Bp + 16 * LDK + k0);
        half8 b2 = *(const half8*)(Bp + 32 * LDK + k0);
        half8 b3 = *(const half8*)(Bp + 48 * LDK + k0);
        acc0 = __builtin_amdgcn_mfma_f32_16x16x32_f16(a, b0, acc0, 0, 0, 0);
        acc1 = __builtin_amdgcn_mfma_f32_16x16x32_f16(a, b1, acc1, 0, 0, 0);
        acc2 = __builtin_amdgcn_mfma_f32_16x16x32_f16(a, b2, acc2, 0, 0, 0);
        acc3 = __builtin_amdgcn_mfma_f32_16x16x32_f16(a, b3, acc3, 0, 0, 0);
    }
    int orow = wv * 16 + (lane >> 4) * 4;
#pragma unroll
    for (int i = 0; i < 4; ++i) {
        long row = rowBase + orow + i;
        if (row >= N_NODES) break;
        float dv = dinv[row];
        __half* op = &out[row * EMB + l15];
        op[0]  = __float2half(dv * acc0[i]);
        op[16] = __float2half(dv * acc1[i]);
        op[32] = __float2half(dv * acc2[i]);
        op[48] = __float2half(dv * acc3[i]);
    }
}

// ---------- FUSED agg(layer l) + gemm(layer l+1) ----------
// agg_l -> gemm_{l+1} is NODE-LOCAL: the 64-row GEMM tile is exactly the 64
// nodes this block aggregates, so h_out never touches global memory -- it goes
// straight into LDS as the MFMA A-tile. 8 waves (512 thr): agg = 8 nodes/wave
// (grid 782x8 = 6256 waves, ~24/CU of gather MLP); MFMA = wave (wv&3) rows
// x (wv>>2) col-half.
__global__ __launch_bounds__(512) void agg_gemm_k(const __half* __restrict__ hs_in,
                                                  const int2* __restrict__ csr,
                                                  const int* __restrict__ row_start,
                                                  const int* __restrict__ row_end,
                                                  const float* __restrict__ dinv,
                                                  const float* __restrict__ b,
                                                  const float* __restrict__ W,
                                                  __half* __restrict__ hs_out) {
    constexpr int K = EMB;       // 64
    constexpr int LDK = K + 8;   // 72
    __shared__ __align__(16) f16 Ao[64 * LDK];
    __shared__ __align__(16) f16 Wt[EMB * LDK];
    int tid = threadIdx.x;
    int wv = tid >> 6, lane = tid & 63;
    long tileBase = (long)blockIdx.x * 64;
    int validRows = (int)min((long)64, (long)N_NODES - tileBase);

    {   // stage W transposed fp32 -> fp16 (Wt[n][k])
        const float4* Wg = (const float4*)W;
        for (int i = tid; i < K * (EMB / 4); i += 512) {
            int k = i >> 4, nq = i & 15;
            float4 v = Wg[i];
            Wt[(4 * nq + 0) * LDK + k] = (f16)v.x;
            Wt[(4 * nq + 1) * LDK + k] = (f16)v.y;
            Wt[(4 * nq + 2) * LDK + k] = (f16)v.z;
            Wt[(4 * nq + 3) * LDK + k] = (f16)v.w;
        }
    }
    {   // phase 1: aggregation, 8 nodes per wave, lane = channel
        const char* hsb = (const char*)hs_in + (size_t)(lane * 2);
        float bl = b[lane];
        for (int i = 0; i < 8; ++i) {
            long node = tileBase + wv * 8 + i;
            if (node >= N_NODES) break;
            float di = dinv[node];
            float acc = __half2float(hs_in[node * EMB + lane]);   // self term
            acc = agg_row(hsb, csr, row_start[node], row_end[node], acc);
            float o = tanhf(di * acc + bl);
            Ao[(wv * 8 + i) * LDK + lane] = (f16)o;
        }
    }
    if (validRows < 64) {   // zero-fill invalid rows (tail block only)
        for (int i = tid; i < (64 - validRows) * (K / 8); i += 512) {
            int r = validRows + i / (K / 8), c = i % (K / 8);
            *(uint4*)&Ao[r * LDK + c * 8] = make_uint4(0, 0, 0, 0);
        }
    }
    __syncthreads();
    {   // phase 2: MFMA 64x64 @ 64x64
        int l15 = lane & 15, kg = (lane >> 4) * 8;
        int r0 = (wv & 3) * 16;
        int ch = (wv >> 2) * 32;
        const f16* Ap  = &Ao[(r0 + l15) * LDK + kg];
        const f16* Bp0 = &Wt[(ch + l15) * LDK + kg];
        const f16* Bp1 = &Wt[(ch + 16 + l15) * LDK + kg];
        f32x4 acc0 = {0.f, 0.f, 0.f, 0.f}, acc1 = acc0;
#pragma unroll
        for (int ks = 0; ks < K / 32; ++ks) {
            int k0 = ks * 32;
            half8 a  = *(const half8*)(Ap + k0);
            half8 b0 = *(const half8*)(Bp0 + k0);
            half8 b1 = *(const half8*)(Bp1 + k0);
            acc0 = __builtin_amdgcn_mfma_f32_16x16x32_f16(a, b0, acc0, 0, 0, 0);
            acc1 = __builtin_amdgcn_mfma_f32_16x16x32_f16(a, b1, acc1, 0, 0, 0);
        }
        int orow = r0 + (lane >> 4) * 4;
#pragma unroll
        for (int i = 0; i < 4; ++i) {
            long row = tileBase + orow + i;
            if (row >= N_NODES) break;
            float dv = dinv[row];
            __half* op = &hs_out[row * EMB + ch + l15];
            op[0]  = __float2half(dv * acc0[i]);
            op[16] = __float2half(dv * acc1[i]);
        }
    }
}

// ---------- pooling helpers ----------
__device__ inline int f2ord(float x) {
    int bb = __float_as_int(x);
    return bb >= 0 ? bb : (bb ^ 0x7fffffff);
}
__device__ inline float ord2f(int k) {
    return __int_as_float(k >= 0 ? k : (k ^ 0x7fffffff));
}

// ---------- FUSED agg(layer 3) + pool ----------
// h3 never hits global: agg writes LDS, waves 0-3 pool 16-node chunks from LDS.
__global__ __launch_bounds__(512) void agg_pool_k(const __half* __restrict__ hs_in,
                                                  const int2* __restrict__ csr,
                                                  const int* __restrict__ row_start,
                                                  const int* __restrict__ row_end,
                                                  const float* __restrict__ dinv,
                                                  const float* __restrict__ b,
                                                  const int* __restrict__ batch,
                                                  int* gmax, float* gsum, int* cnt) {
    __shared__ float Ho[64 * EMB];
    int tid = threadIdx.x;
    int wv = tid >> 6, lane = tid & 63;
    long tileBase = (long)blockIdx.x * 64;

    {
        const char* hsb = (const char*)hs_in + (size_t)(lane * 2);
        float bl = b[lane];
        for (int i = 0; i < 8; ++i) {
            long node = tileBase + wv * 8 + i;
            if (node >= N_NODES) break;
            float di = dinv[node];
            float acc = __half2float(hs_in[node * EMB + lane]);
            acc = agg_row(hsb, csr, row_start[node], row_end[node], acc);
            Ho[(wv * 8 + i) * EMB + lane] = tanhf(di * acc + bl);
        }
    }
    __syncthreads();
    if (wv < 4) {
        long start = tileBase + wv * POOL_CHUNK;
        if (start >= N_NODES) return;   // 50000 % 16 == 0 -> full chunks when valid
        int bsel = (lane < POOL_CHUNK) ? batch[start + lane] : 0;
        float v[POOL_CHUNK];
#pragma unroll
        for (int i = 0; i < POOL_CHUNK; ++i)
            v[i] = Ho[(wv * 16 + i) * EMB + lane];
        int curg = __shfl(bsel, 0);
        float mx = -INFINITY, sm = 0.f;
        int ct = 0;
#pragma unroll
        for (int i = 0; i < POOL_CHUNK; ++i) {
            int g = __shfl(bsel, i);
            if (g != curg) {
                atomicMax(&gmax[curg * EMB + lane], f2ord(mx));
                atomicAdd(&gsum[curg * EMB + lane], sm);
                if (lane == 0) atomicAdd(&cnt[curg], ct);
                curg = g; mx = -INFINITY; sm = 0.f; ct = 0;
            }
            mx = fmaxf(mx, v[i]);
            sm += v[i];
            ++ct;
        }
        atomicMax(&gmax[curg * EMB + lane], f2ord(mx));
        atomicAdd(&gsum[curg * EMB + lane], sm);
        if (lane == 0) atomicAdd(&cnt[curg], ct);
    }
}

__global__ void final_k(const int* __restrict__ gmax, const float* __restrict__ gsum,
                        const int* __restrict__ cnt, const float* __restrict__ Wout,
                        const float* __restrict__ bout, float* __restrict__ out) {
    int g = threadIdx.x;
    if (g >= N_GRAPHS) return;
    float c = fmaxf((float)cnt[g], 1.0f);
    float acc = bout[0];
    for (int ch = 0; ch < EMB; ++ch) {
        acc += ord2f(gmax[g * EMB + ch]) * Wout[ch]
             + (gsum[g * EMB + ch] / c) * Wout[EMB + ch];
    }
    out[g] = acc;
}

extern "C" void kernel_launch(void* const* d_in, const int* in_sizes, int n_in,
                              void* d_out, int out_size, void* d_ws, size_t ws_size,
                              hipStream_t stream) {
    const float* x         = (const float*)d_in[0];
    const int*   edge_idx  = (const int*)d_in[1];
    const float* edge_attr = (const float*)d_in[2];
    const int*   batch     = (const int*)d_in[3];
    const float* W0 = (const float*)d_in[4];
    const float* b0 = (const float*)d_in[5];
    const float* W1 = (const float*)d_in[6];
    const float* b1 = (const float*)d_in[7];
    const float* W2 = (const float*)d_in[8];
    const float* b2 = (const float*)d_in[9];
    const float* W3 = (const float*)d_in[10];
    const float* b3 = (const float*)d_in[11];
    const float* Wout = (const float*)d_in[12];
    const float* bout = (const float*)d_in[13];
    float* out = (float*)d_out;

    const int* src = edge_idx;            // edge_index[0]
    const int* dst = edge_idx + N_EDGES;  // edge_index[1]

    // workspace layout (~33 MB)
    char* ws = (char*)d_ws;
    float*  dinv      = (float*)ws;  ws += (size_t)N_NODES * sizeof(float);
    unsigned long long* cnt64 = (unsigned long long*)ws;
    ws += (size_t)N_NODES * CPAD64 * sizeof(unsigned long long);
    int*    row_start = (int*)ws;    ws += (size_t)N_NODES * sizeof(int);
    int*    row_end   = (int*)ws;    ws += (size_t)N_NODES * sizeof(int);
    int*    slot_in   = (int*)ws;    ws += (size_t)N_EDGES * sizeof(int);
    int*    total     = (int*)ws;    ws += 4 * sizeof(int);  // keep 16B alignment
    int2*   csr       = (int2*)ws;   ws += (size_t)N_EDGES * sizeof(int2);
    __half* bufL      = (__half*)ws; ws += (size_t)N_NODES * EMB * sizeof(__half);
    __half* bufM      = (__half*)ws; ws += (size_t)N_NODES * EMB * sizeof(__half);
    int*    gmax      = (int*)ws;    ws += N_GRAPHS * EMB * sizeof(int);
    float*  gsum      = (float*)ws;  ws += N_GRAPHS * EMB * sizeof(float);
    int*    cnt       = (int*)ws;    ws += N_GRAPHS * sizeof(int);

    const int nodeB = (N_NODES + 255) / 256;
    const int edgeB = (N_EDGES + 255) / 256;
    const int gemmB = (N_NODES + 63) / 64;   // 782 blocks, 64-node tiles
    const int initB = (N_NODES * CPAD64 + 255) / 256;

    // CSR precompute (norm fully folded; count+weighted-degree via ONE 64b atomic)
    init_k<<<initB, 256, 0, stream>>>(cnt64, total, gmax, gsum, cnt);
    hist_k<<<edgeB, 256, 0, stream>>>(dst, edge_attr, cnt64, slot_in);
    alloc_k<<<nodeB, 256, 0, stream>>>(cnt64, row_start, row_end, total, dinv);
    scatter_k<<<edgeB, 256, 0, stream>>>(src, dst, edge_attr, slot_in, row_start, csr);

    // layer pipeline: gemm0, then fused agg_l+gemm_{l+1}, then fused agg3+pool
    gemm_k<IN_CH, false><<<gemmB, 256, 0, stream>>>(x, W0, dinv, bufL);
    agg_gemm_k<<<gemmB, 512, 0, stream>>>(bufL, csr, row_start, row_end, dinv, b0, W1, bufM);
    agg_gemm_k<<<gemmB, 512, 0, stream>>>(bufM, csr, row_start, row_end, dinv, b1, W2, bufL);
    agg_gemm_k<<<gemmB, 512, 0, stream>>>(bufL, csr, row_start, row_end, dinv, b2, W3, bufM);
    agg_pool_k<<<gemmB, 512, 0, stream>>>(bufM, csr, row_start, row_end, dinv, b3,
                                          batch, gmax, gsum, cnt);
    final_k<<<1, 64, 0, stream>>>(gmax, gsum, cnt, Wout, bout, out);
}

// Round 9
// 317.732 us; speedup vs baseline: 1.3069x; 1.0051x over previous
//
#include <hip/hip_runtime.h>
#include <hip/hip_fp16.h>
#include <math.h>
#include <limits.h>

#define N_NODES 50000
#define N_EDGES 800000
#define N_GRAPHS 64
#define IN_CH 128
#define EMB 64
#define POOL_CHUNK 16   // 50000 = 16 * 3125 exactly
#define CPAD64 16       // one 128B line per node: single u64 = (count<<44) | wsum_fx24
#define CNT_SHIFT 44
#define FX_SCALE 16777216.0f   // 2^24 fixed-point for edge weights (w in [0,1))
#define BM 32           // fused-kernel tile: 32 nodes -> 1563 blocks (~6/CU, 32 waves/CU)

typedef _Float16 f16;
typedef __attribute__((ext_vector_type(8))) _Float16 half8;
typedef __attribute__((ext_vector_type(4))) float f32x4;

// ---------- init: packed counters=0, total=0, pool accumulators ----------
__global__ void init_k(unsigned long long* cnt64, int* total, int* gmax,
                       float* gsum, int* cnt) {
    int i = blockIdx.x * blockDim.x + threadIdx.x;
    if (i < N_NODES * CPAD64) cnt64[i] = 0ULL;
    if (i == 0) *total = 0;
    if (i < N_GRAPHS * EMB) { gmax[i] = INT_MIN; gsum[i] = 0.f; }
    if (i < N_GRAPHS) cnt[i] = 0;
}

// ---------- histogram: ONE packed 64-bit atomic per edge ----------
__global__ void hist_k(const int* __restrict__ dst, const float* __restrict__ w,
                       unsigned long long* cnt64, int* __restrict__ slot_in) {
    int e = blockIdx.x * blockDim.x + threadIdx.x;
    if (e >= N_EDGES) return;
    unsigned long long fx = (unsigned long long)(w[e] * FX_SCALE + 0.5f);
    unsigned long long old = atomicAdd(&cnt64[(size_t)dst[e] * CPAD64],
                                       (1ULL << CNT_SHIFT) | fx);
    slot_in[e] = (int)(old >> CNT_SHIFT);
}

// ---------- CSR range allocation: wave-scan + one atomic per wave; dinv folded ----------
__global__ void alloc_k(const unsigned long long* __restrict__ cnt64,
                        int* __restrict__ row_start, int* __restrict__ row_end,
                        int* total, float* __restrict__ dinv) {
    int i = blockIdx.x * blockDim.x + threadIdx.x;
    int lane = threadIdx.x & 63;
    unsigned long long v = (i < N_NODES) ? cnt64[(size_t)i * CPAD64] : 0ULL;
    int c = (int)(v >> CNT_SHIFT);
    int inc = c;
    for (int off = 1; off < 64; off <<= 1) {
        int t = __shfl_up(inc, off);
        if (lane >= off) inc += t;
    }
    int base;
    if (lane == 63) base = atomicAdd(total, inc);
    base = __shfl(base, 63);
    int excl = base + inc - c;
    if (i < N_NODES) {
        row_start[i] = excl;
        row_end[i] = excl + c;
        float degw = (float)(v & ((1ULL << CNT_SHIFT) - 1)) * (1.0f / FX_SCALE);
        float d = 1.0f + degw;  // + self-loop weight 1
        dinv[i] = d > 0.f ? rsqrtf(d) : 0.f;
    }
}

// ---------- scatter edges into CSR slots (atomic-free) ----------
// csr.x = src * EMB * 2 (BYTE offset into fp16 feature buffer); csr.y = raw w.
__global__ void scatter_k(const int* __restrict__ src, const int* __restrict__ dst,
                          const float* __restrict__ w, const int* __restrict__ slot_in,
                          const int* __restrict__ row_start, int2* __restrict__ csr) {
    int e = blockIdx.x * blockDim.x + threadIdx.x;
    if (e >= N_EDGES) return;
    int d = dst[e];
    int slot = row_start[d] + slot_in[e];
    csr[slot] = make_int2(src[e] * (EMB * 2), __float_as_int(w[e]));
}

// ---------- shared agg inner: acc += sum over CSR row (lane = channel) ----------
// 16-edge batches: ONE lane-spread csr load (128B, 2 lines, 1 instr) + readlane
// -> SGPR (src,w); 16 gathers in flight. Then one 8-batch, then clamped tail.
__device__ inline float agg_row(const char* hsb, const int2* __restrict__ csr,
                                int e, int end, float acc) {
    int lane = threadIdx.x & 63;
    for (; e + 15 < end; e += 16) {
        int2 rl = csr[e + (lane & 15)];
        int so[16], wb[16];
#pragma unroll
        for (int j = 0; j < 16; ++j) {
            so[j] = __builtin_amdgcn_readlane(rl.x, j);
            wb[j] = __builtin_amdgcn_readlane(rl.y, j);
        }
        __half v[16];
#pragma unroll
        for (int j = 0; j < 16; ++j) v[j] = *(const __half*)(hsb + (unsigned)so[j]);
#pragma unroll
        for (int j = 0; j < 16; ++j) acc += __int_as_float(wb[j]) * __half2float(v[j]);
    }
    if (e + 7 < end) {
        int2 rl = csr[e + (lane & 7)];
        int so[8], wb[8];
#pragma unroll
        for (int j = 0; j < 8; ++j) {
            so[j] = __builtin_amdgcn_readlane(rl.x, j);
            wb[j] = __builtin_amdgcn_readlane(rl.y, j);
        }
        __half v[8];
#pragma unroll
        for (int j = 0; j < 8; ++j) v[j] = *(const __half*)(hsb + (unsigned)so[j]);
#pragma unroll
        for (int j = 0; j < 8; ++j) acc += __int_as_float(wb[j]) * __half2float(v[j]);
        e += 8;
    }
    int n = end - e;   // 0..7, uniform per node
    if (n > 0) {
        int idx = e + (lane & 7);
        if (idx >= end) idx = end - 1;
        int2 rl = csr[idx];
#pragma unroll
        for (int j = 0; j < 8; ++j) {
            if (j < n) {
                int so = __builtin_amdgcn_readlane(rl.x, j);
                int wb = __builtin_amdgcn_readlane(rl.y, j);
                acc += __int_as_float(wb) * __half2float(*(const __half*)(hsb + (unsigned)so));
            }
        }
    }
    return acc;
}

// ---------- hs = dinv * (A @ W) via MFMA 16x16x32 f16 (layer 0, fp32 input) ----------
template<int K, bool HALF_IN>
__global__ __launch_bounds__(256) void gemm_k(const void* __restrict__ A_,
                                              const float* __restrict__ W,
                                              const float* __restrict__ dinv,
                                              __half* __restrict__ out) {
    constexpr int LDK = K + 8;
    __shared__ __align__(16) f16 Al[64 * LDK];
    __shared__ __align__(16) f16 Wt[EMB * LDK];   // Wt[n][k]
    int tid = threadIdx.x;
    long rowBase = (long)blockIdx.x * 64;
    int validRows = (int)min((long)64, (long)N_NODES - rowBase);

    if constexpr (HALF_IN) {
        const __half* Ah = (const __half*)A_ + rowBase * K;
        constexpr int CH = K / 8;
        for (int i = tid; i < validRows * CH; i += 256) {
            int r = i / CH, c = i % CH;
            uint4 v = *(const uint4*)(Ah + (long)r * K + c * 8);
            *(uint4*)&Al[r * LDK + c * 8] = v;
        }
    } else {
        const float* Af = (const float*)A_;
        constexpr int CH = K / 4;
        for (int i = tid; i < validRows * CH; i += 256) {
            int r = i / CH, c = i % CH;
            float4 v = *(const float4*)(Af + (rowBase + r) * K + c * 4);
            __half2 p0 = __floats2half2_rn(v.x, v.y);
            __half2 p1 = __floats2half2_rn(v.z, v.w);
            uint2 u = make_uint2(*(unsigned int*)&p0, *(unsigned int*)&p1);
            *(uint2*)&Al[r * LDK + c * 4] = u;
        }
    }
    {   // zero-fill invalid rows (last block only)
        constexpr int CZ = K / 8;
        for (int i = tid + validRows * CZ; i < 64 * CZ; i += 256) {
            int r = i / CZ, c = i % CZ;
            *(uint4*)&Al[r * LDK + c * 8] = make_uint4(0, 0, 0, 0);
        }
    }
    {   // stage W transposed fp32 -> fp16
        const float4* Wg = (const float4*)W;
        for (int i = tid; i < K * (EMB / 4); i += 256) {
            int k = i >> 4, nq = i & 15;
            float4 v = Wg[i];
            Wt[(4 * nq + 0) * LDK + k] = (f16)v.x;
            Wt[(4 * nq + 1) * LDK + k] = (f16)v.y;
            Wt[(4 * nq + 2) * LDK + k] = (f16)v.z;
            Wt[(4 * nq + 3) * LDK + k] = (f16)v.w;
        }
    }
    __syncthreads();

    int wv = tid >> 6, lane = tid & 63;
    int l15 = lane & 15, kg = (lane >> 4) * 8;
    const f16* Ap = &Al[(wv * 16 + l15) * LDK + kg];
    const f16* Bp = &Wt[l15 * LDK + kg];
    f32x4 acc0 = {0.f, 0.f, 0.f, 0.f};
    f32x4 acc1 = acc0, acc2 = acc0, acc3 = acc0;
#pragma unroll
    for (int ks = 0; ks < K / 32; ++ks) {
        int k0 = ks * 32;
        half8 a  = *(const half8*)(Ap + k0);
        half8 b0 = *(const half8*)(Bp + k0);
        half8 b1 = *(const half8*)(Bp + 16 * LDK + k0);
        half8 b2 = *(const half8*)(Bp + 32 * LDK + k0);
        half8 b3 = *(const half8*)(Bp + 48 * LDK + k0);
        acc0 = __builtin_amdgcn_mfma_f32_16x16x32_f16(a, b0, acc0, 0, 0, 0);
        acc1 = __builtin_amdgcn_mfma_f32_16x16x32_f16(a, b1, acc1, 0, 0, 0);
        acc2 = __builtin_amdgcn_mfma_f32_16x16x32_f16(a, b2, acc2, 0, 0, 0);
        acc3 = __builtin_amdgcn_mfma_f32_16x16x32_f16(a, b3, acc3, 0, 0, 0);
    }
    int orow = wv * 16 + (lane >> 4) * 4;
#pragma unroll
    for (int i = 0; i < 4; ++i) {
        long row = rowBase + orow + i;
        if (row >= N_NODES) break;
        float dv = dinv[row];
        __half* op = &out[row * EMB + l15];
        op[0]  = __float2half(dv * acc0[i]);
        op[16] = __float2half(dv * acc1[i]);
        op[32] = __float2half(dv * acc2[i]);
        op[48] = __float2half(dv * acc3[i]);
    }
}

// ---------- FUSED agg(layer l) + gemm(layer l+1), BM=32 tile ----------
// agg_l -> gemm_{l+1} is NODE-LOCAL. 8 waves (512 thr): agg = 4 nodes/wave
// (1563 blocks -> 32 waves/CU, halved serial chain); MFMA = one 16x16 output
// tile per wave (rows (wv&1)*16, cols (wv>>1)*16, K=64 -> 2 MFMAs).
__global__ __launch_bounds__(512) void agg_gemm_k(const __half* __restrict__ hs_in,
                                                  const int2* __restrict__ csr,
                                                  const int* __restrict__ row_start,
                                                  const int* __restrict__ row_end,
                                                  const float* __restrict__ dinv,
                                                  const float* __restrict__ b,
                                                  const float* __restrict__ W,
                                                  __half* __restrict__ hs_out) {
    constexpr int K = EMB;       // 64
    constexpr int LDK = K + 8;   // 72
    __shared__ __align__(16) f16 Ao[BM * LDK];
    __shared__ __align__(16) f16 Wt[EMB * LDK];
    int tid = threadIdx.x;
    int wv = tid >> 6, lane = tid & 63;
    long tileBase = (long)blockIdx.x * BM;
    int validRows = (int)min((long)BM, (long)N_NODES - tileBase);

    {   // stage W transposed fp32 -> fp16 (Wt[n][k])
        const float4* Wg = (const float4*)W;
        for (int i = tid; i < K * (EMB / 4); i += 512) {
            int k = i >> 4, nq = i & 15;
            float4 v = Wg[i];
            Wt[(4 * nq + 0) * LDK + k] = (f16)v.x;
            Wt[(4 * nq + 1) * LDK + k] = (f16)v.y;
            Wt[(4 * nq + 2) * LDK + k] = (f16)v.z;
            Wt[(4 * nq + 3) * LDK + k] = (f16)v.w;
        }
    }
    {   // phase 1: aggregation, 4 nodes per wave, lane = channel
        const char* hsb = (const char*)hs_in + (size_t)(lane * 2);
        float bl = b[lane];
        for (int i = 0; i < 4; ++i) {
            long node = tileBase + wv * 4 + i;
            if (node >= N_NODES) break;
            float di = dinv[node];
            float acc = __half2float(hs_in[node * EMB + lane]);   // self term
            acc = agg_row(hsb, csr, row_start[node], row_end[node], acc);
            float o = tanhf(di * acc + bl);
            Ao[(wv * 4 + i) * LDK + lane] = (f16)o;
        }
    }
    if (validRows < BM) {   // zero-fill invalid rows (tail block only)
        for (int i = tid; i < (BM - validRows) * (K / 8); i += 512) {
            int r = validRows + i / (K / 8), c = i % (K / 8);
            *(uint4*)&Ao[r * LDK + c * 8] = make_uint4(0, 0, 0, 0);
        }
    }
    __syncthreads();
    {   // phase 2: MFMA 32x64 @ 64x64
        int l15 = lane & 15, kg = (lane >> 4) * 8;
        int r0 = (wv & 1) * 16;
        int c0 = (wv >> 1) * 16;
        const f16* Ap = &Ao[(r0 + l15) * LDK + kg];
        const f16* Bp = &Wt[(c0 + l15) * LDK + kg];
        f32x4 acc = {0.f, 0.f, 0.f, 0.f};
#pragma unroll
        for (int ks = 0; ks < K / 32; ++ks) {
            int k0 = ks * 32;
            half8 a  = *(const half8*)(Ap + k0);
            half8 bb = *(const half8*)(Bp + k0);
            acc = __builtin_amdgcn_mfma_f32_16x16x32_f16(a, bb, acc, 0, 0, 0);
        }
        int orow = r0 + (lane >> 4) * 4;
#pragma unroll
        for (int i = 0; i < 4; ++i) {
            long row = tileBase + orow + i;
            if (row >= N_NODES) break;
            float dv = dinv[row];
            hs_out[row * EMB + c0 + l15] = __float2half(dv * acc[i]);
        }
    }
}

// ---------- pooling helpers ----------
__device__ inline int f2ord(float x) {
    int bb = __float_as_int(x);
    return bb >= 0 ? bb : (bb ^ 0x7fffffff);
}
__device__ inline float ord2f(int k) {
    return __int_as_float(k >= 0 ? k : (k ^ 0x7fffffff));
}

// ---------- FUSED agg(layer 3) + pool, BM=32 tile ----------
__global__ __launch_bounds__(512) void agg_pool_k(const __half* __restrict__ hs_in,
                                                  const int2* __restrict__ csr,
                                                  const int* __restrict__ row_start,
                                                  const int* __restrict__ row_end,
                                                  const float* __restrict__ dinv,
                                                  const float* __restrict__ b,
                                                  const int* __restrict__ batch,
                                                  int* gmax, float* gsum, int* cnt) {
    __shared__ float Ho[BM * EMB];
    int tid = threadIdx.x;
    int wv = tid >> 6, lane = tid & 63;
    long tileBase = (long)blockIdx.x * BM;

    {
        const char* hsb = (const char*)hs_in + (size_t)(lane * 2);
        float bl = b[lane];
        for (int i = 0; i < 4; ++i) {
            long node = tileBase + wv * 4 + i;
            if (node >= N_NODES) break;
            float di = dinv[node];
            float acc = __half2float(hs_in[node * EMB + lane]);
            acc = agg_row(hsb, csr, row_start[node], row_end[node], acc);
            Ho[(wv * 4 + i) * EMB + lane] = tanhf(di * acc + bl);
        }
    }
    __syncthreads();
    if (wv < BM / POOL_CHUNK) {   // waves 0-1 pool the two 16-node chunks
        long start = tileBase + wv * POOL_CHUNK;
        if (start >= N_NODES) return;   // 50000 % 16 == 0 -> full chunks when valid
        int bsel = (lane < POOL_CHUNK) ? batch[start + lane] : 0;
        float v[POOL_CHUNK];
#pragma unroll
        for (int i = 0; i < POOL_CHUNK; ++i)
            v[i] = Ho[(wv * POOL_CHUNK + i) * EMB + lane];
        int curg = __shfl(bsel, 0);
        float mx = -INFINITY, sm = 0.f;
        int ct = 0;
#pragma unroll
        for (int i = 0; i < POOL_CHUNK; ++i) {
            int g = __shfl(bsel, i);
            if (g != curg) {
                atomicMax(&gmax[curg * EMB + lane], f2ord(mx));
                atomicAdd(&gsum[curg * EMB + lane], sm);
                if (lane == 0) atomicAdd(&cnt[curg], ct);
                curg = g; mx = -INFINITY; sm = 0.f; ct = 0;
            }
            mx = fmaxf(mx, v[i]);
            sm += v[i];
            ++ct;
        }
        atomicMax(&gmax[curg * EMB + lane], f2ord(mx));
        atomicAdd(&gsum[curg * EMB + lane], sm);
        if (lane == 0) atomicAdd(&cnt[curg], ct);
    }
}

__global__ void final_k(const int* __restrict__ gmax, const float* __restrict__ gsum,
                        const int* __restrict__ cnt, const float* __restrict__ Wout,
                        const float* __restrict__ bout, float* __restrict__ out) {
    int g = threadIdx.x;
    if (g >= N_GRAPHS) return;
    float c = fmaxf((float)cnt[g], 1.0f);
    float acc = bout[0];
    for (int ch = 0; ch < EMB; ++ch) {
        acc += ord2f(gmax[g * EMB + ch]) * Wout[ch]
             + (gsum[g * EMB + ch] / c) * Wout[EMB + ch];
    }
    out[g] = acc;
}

extern "C" void kernel_launch(void* const* d_in, const int* in_sizes, int n_in,
                              void* d_out, int out_size, void* d_ws, size_t ws_size,
                              hipStream_t stream) {
    const float* x         = (const float*)d_in[0];
    const int*   edge_idx  = (const int*)d_in[1];
    const float* edge_attr = (const float*)d_in[2];
    const int*   batch     = (const int*)d_in[3];
    const float* W0 = (const float*)d_in[4];
    const float* b0 = (const float*)d_in[5];
    const float* W1 = (const float*)d_in[6];
    const float* b1 = (const float*)d_in[7];
    const float* W2 = (const float*)d_in[8];
    const float* b2 = (const float*)d_in[9];
    const float* W3 = (const float*)d_in[10];
    const float* b3 = (const float*)d_in[11];
    const float* Wout = (const float*)d_in[12];
    const float* bout = (const float*)d_in[13];
    float* out = (float*)d_out;

    const int* src = edge_idx;            // edge_index[0]
    const int* dst = edge_idx + N_EDGES;  // edge_index[1]

    // workspace layout (~33 MB)
    char* ws = (char*)d_ws;
    float*  dinv      = (float*)ws;  ws += (size_t)N_NODES * sizeof(float);
    unsigned long long* cnt64 = (unsigned long long*)ws;
    ws += (size_t)N_NODES * CPAD64 * sizeof(unsigned long long);
    int*    row_start = (int*)ws;    ws += (size_t)N_NODES * sizeof(int);
    int*    row_end   = (int*)ws;    ws += (size_t)N_NODES * sizeof(int);
    int*    slot_in   = (int*)ws;    ws += (size_t)N_EDGES * sizeof(int);
    int*    total     = (int*)ws;    ws += 4 * sizeof(int);  // keep 16B alignment
    int2*   csr       = (int2*)ws;   ws += (size_t)N_EDGES * sizeof(int2);
    __half* bufL      = (__half*)ws; ws += (size_t)N_NODES * EMB * sizeof(__half);
    __half* bufM      = (__half*)ws; ws += (size_t)N_NODES * EMB * sizeof(__half);
    int*    gmax      = (int*)ws;    ws += N_GRAPHS * EMB * sizeof(int);
    float*  gsum      = (float*)ws;  ws += N_GRAPHS * EMB * sizeof(float);
    int*    cnt       = (int*)ws;    ws += N_GRAPHS * sizeof(int);

    const int nodeB  = (N_NODES + 255) / 256;
    const int edgeB  = (N_EDGES + 255) / 256;
    const int gemm0B = (N_NODES + 63) / 64;   // 782 blocks, 64-node tiles
    const int fuseB  = (N_NODES + BM - 1) / BM;  // 1563 blocks, 32-node tiles
    const int initB  = (N_NODES * CPAD64 + 255) / 256;

    // CSR precompute (norm fully folded; count+weighted-degree via ONE 64b atomic)
    init_k<<<initB, 256, 0, stream>>>(cnt64, total, gmax, gsum, cnt);
    hist_k<<<edgeB, 256, 0, stream>>>(dst, edge_attr, cnt64, slot_in);
    alloc_k<<<nodeB, 256, 0, stream>>>(cnt64, row_start, row_end, total, dinv);
    scatter_k<<<edgeB, 256, 0, stream>>>(src, dst, edge_attr, slot_in, row_start, csr);

    // layer pipeline: gemm0, then fused agg_l+gemm_{l+1}, then fused agg3+pool
    gemm_k<IN_CH, false><<<gemm0B, 256, 0, stream>>>(x, W0, dinv, bufL);
    agg_gemm_k<<<fuseB, 512, 0, stream>>>(bufL, csr, row_start, row_end, dinv, b0, W1, bufM);
    agg_gemm_k<<<fuseB, 512, 0, stream>>>(bufM, csr, row_start, row_end, dinv, b1, W2, bufL);
    agg_gemm_k<<<fuseB, 512, 0, stream>>>(bufL, csr, row_start, row_end, dinv, b2, W3, bufM);
    agg_pool_k<<<fuseB, 512, 0, stream>>>(bufM, csr, row_start, row_end, dinv, b3,
                                          batch, gmax, gsum, cnt);
    final_k<<<1, 64, 0, stream>>>(gmax, gsum, cnt, Wout, bout, out);
}

// Round 10
// 309.132 us; speedup vs baseline: 1.3432x; 1.0278x over previous
//
#include <hip/hip_runtime.h>
#include <hip/hip_fp16.h>
#include <math.h>
#include <limits.h>

#define N_NODES 50000
#define N_EDGES 800000
#define N_GRAPHS 64
#define IN_CH 128
#define EMB 64
#define POOL_CHUNK 16   // 50000 = 16 * 3125 exactly
#define CPAD64 16       // one 128B line per node: single u64 = (count<<44) | wsum_fx24
#define CNT_SHIFT 44
#define FX_SCALE 16777216.0f   // 2^24 fixed-point for edge weights (w in [0,1))
#define BM 32           // fused-kernel tile: 32 nodes (half of a 64-node alloc group)
#define ECAP 2048       // LDS csr stage capacity (mean 512/tile, sigma ~23 -> never hit)

typedef _Float16 f16;
typedef __attribute__((ext_vector_type(8))) _Float16 half8;
typedef __attribute__((ext_vector_type(4))) float f32x4;

// ---------- init: packed counters=0, total=0, pool accumulators ----------
__global__ void init_k(unsigned long long* cnt64, int* total, int* gmax,
                       float* gsum, int* cnt) {
    int i = blockIdx.x * blockDim.x + threadIdx.x;
    if (i < N_NODES * CPAD64) cnt64[i] = 0ULL;
    if (i == 0) *total = 0;
    if (i < N_GRAPHS * EMB) { gmax[i] = INT_MIN; gsum[i] = 0.f; }
    if (i < N_GRAPHS) cnt[i] = 0;
}

// ---------- histogram: ONE packed 64-bit atomic per edge ----------
__global__ void hist_k(const int* __restrict__ dst, const float* __restrict__ w,
                       unsigned long long* cnt64, int* __restrict__ slot_in) {
    int e = blockIdx.x * blockDim.x + threadIdx.x;
    if (e >= N_EDGES) return;
    unsigned long long fx = (unsigned long long)(w[e] * FX_SCALE + 0.5f);
    unsigned long long old = atomicAdd(&cnt64[(size_t)dst[e] * CPAD64],
                                       (1ULL << CNT_SHIFT) | fx);
    slot_in[e] = (int)(old >> CNT_SHIFT);
}

// ---------- CSR range allocation: wave-scan + one atomic per wave; dinv folded ----
// NOTE: one atomicAdd per 64-node group + ascending prefix => every 64-aligned
// node group (hence every BM=32 tile) owns a CONTIGUOUS csr range. The fused
// kernels rely on this to stage their csr slice in LDS.
__global__ void alloc_k(const unsigned long long* __restrict__ cnt64,
                        int* __restrict__ row_start, int* __restrict__ row_end,
                        int* total, float* __restrict__ dinv) {
    int i = blockIdx.x * blockDim.x + threadIdx.x;
    int lane = threadIdx.x & 63;
    unsigned long long v = (i < N_NODES) ? cnt64[(size_t)i * CPAD64] : 0ULL;
    int c = (int)(v >> CNT_SHIFT);
    int inc = c;
    for (int off = 1; off < 64; off <<= 1) {
        int t = __shfl_up(inc, off);
        if (lane >= off) inc += t;
    }
    int base;
    if (lane == 63) base = atomicAdd(total, inc);
    base = __shfl(base, 63);
    int excl = base + inc - c;
    if (i < N_NODES) {
        row_start[i] = excl;
        row_end[i] = excl + c;
        float degw = (float)(v & ((1ULL << CNT_SHIFT) - 1)) * (1.0f / FX_SCALE);
        float d = 1.0f + degw;  // + self-loop weight 1
        dinv[i] = d > 0.f ? rsqrtf(d) : 0.f;
    }
}

// ---------- scatter edges into CSR slots (atomic-free) ----------
// csr.x = src * EMB * 2 (BYTE offset into fp16 feature buffer); csr.y = raw w.
__global__ void scatter_k(const int* __restrict__ src, const int* __restrict__ dst,
                          const float* __restrict__ w, const int* __restrict__ slot_in,
                          const int* __restrict__ row_start, int2* __restrict__ csr) {
    int e = blockIdx.x * blockDim.x + threadIdx.x;
    if (e >= N_EDGES) return;
    int d = dst[e];
    int slot = row_start[d] + slot_in[e];
    csr[slot] = make_int2(src[e] * (EMB * 2), __float_as_int(w[e]));
}

// ---------- agg inner: acc += sum over edge array slice (lane = channel) ----------
// earr is either the LDS-staged slice (ds_read broadcast, ~free) or global csr
// (fallback, never hit for random data). 8 gathers in flight per batch; the
// only long-latency ops are the feature gathers themselves.
__device__ __forceinline__ float agg_row(const char* hsb, const int2* earr,
                                         int e, int end, float acc) {
    for (; e + 7 < end; e += 8) {
        int2 r[8];
#pragma unroll
        for (int j = 0; j < 8; ++j) r[j] = earr[e + j];
        __half v[8];
#pragma unroll
        for (int j = 0; j < 8; ++j) v[j] = *(const __half*)(hsb + (unsigned)r[j].x);
#pragma unroll
        for (int j = 0; j < 8; ++j) acc += __int_as_float(r[j].y) * __half2float(v[j]);
    }
    for (; e < end; ++e) {
        int2 r = earr[e];
        acc += __int_as_float(r.y) * __half2float(*(const __half*)(hsb + (unsigned)r.x));
    }
    return acc;
}

// ---------- hs = dinv * (A @ W) via MFMA 16x16x32 f16 (layer 0, fp32 input) ----------
template<int K, bool HALF_IN>
__global__ __launch_bounds__(256) void gemm_k(const void* __restrict__ A_,
                                              const float* __restrict__ W,
                                              const float* __restrict__ dinv,
                                              __half* __restrict__ out) {
    constexpr int LDK = K + 8;
    __shared__ __align__(16) f16 Al[64 * LDK];
    __shared__ __align__(16) f16 Wt[EMB * LDK];   // Wt[n][k]
    int tid = threadIdx.x;
    long rowBase = (long)blockIdx.x * 64;
    int validRows = (int)min((long)64, (long)N_NODES - rowBase);

    if constexpr (HALF_IN) {
        const __half* Ah = (const __half*)A_ + rowBase * K;
        constexpr int CH = K / 8;
        for (int i = tid; i < validRows * CH; i += 256) {
            int r = i / CH, c = i % CH;
            uint4 v = *(const uint4*)(Ah + (long)r * K + c * 8);
            *(uint4*)&Al[r * LDK + c * 8] = v;
        }
    } else {
        const float* Af = (const float*)A_;
        constexpr int CH = K / 4;
        for (int i = tid; i < validRows * CH; i += 256) {
            int r = i / CH, c = i % CH;
            float4 v = *(const float4*)(Af + (rowBase + r) * K + c * 4);
            __half2 p0 = __floats2half2_rn(v.x, v.y);
            __half2 p1 = __floats2half2_rn(v.z, v.w);
            uint2 u = make_uint2(*(unsigned int*)&p0, *(unsigned int*)&p1);
            *(uint2*)&Al[r * LDK + c * 4] = u;
        }
    }
    {   // zero-fill invalid rows (last block only)
        constexpr int CZ = K / 8;
        for (int i = tid + validRows * CZ; i < 64 * CZ; i += 256) {
            int r = i / CZ, c = i % CZ;
            *(uint4*)&Al[r * LDK + c * 8] = make_uint4(0, 0, 0, 0);
        }
    }
    {   // stage W transposed fp32 -> fp16
        const float4* Wg = (const float4*)W;
        for (int i = tid; i < K * (EMB / 4); i += 256) {
            int k = i >> 4, nq = i & 15;
            float4 v = Wg[i];
            Wt[(4 * nq + 0) * LDK + k] = (f16)v.x;
            Wt[(4 * nq + 1) * LDK + k] = (f16)v.y;
            Wt[(4 * nq + 2) * LDK + k] = (f16)v.z;
            Wt[(4 * nq + 3) * LDK + k] = (f16)v.w;
        }
    }
    __syncthreads();

    int wv = tid >> 6, lane = tid & 63;
    int l15 = lane & 15, kg = (lane >> 4) * 8;
    const f16* Ap = &Al[(wv * 16 + l15) * LDK + kg];
    const f16* Bp = &Wt[l15 * LDK + kg];
    f32x4 acc0 = {0.f, 0.f, 0.f, 0.f};
    f32x4 acc1 = acc0, acc2 = acc0, acc3 = acc0;
#pragma unroll
    for (int ks = 0; ks < K / 32; ++ks) {
        int k0 = ks * 32;
        half8 a  = *(const half8*)(Ap + k0);
        half8 b0 = *(const half8*)(Bp + k0);
        half8 b1 = *(const half8*)(Bp + 16 * LDK + k0);
        half8 b2 = *(const half8*)(Bp + 32 * LDK + k0);
        half8 b3 = *(const half8*)(Bp + 48 * LDK + k0);
        acc0 = __builtin_amdgcn_mfma_f32_16x16x32_f16(a, b0, acc0, 0, 0, 0);
        acc1 = __builtin_amdgcn_mfma_f32_16x16x32_f16(a, b1, acc1, 0, 0, 0);
        acc2 = __builtin_amdgcn_mfma_f32_16x16x32_f16(a, b2, acc2, 0, 0, 0);
        acc3 = __builtin_amdgcn_mfma_f32_16x16x32_f16(a, b3, acc3, 0, 0, 0);
    }
    int orow = wv * 16 + (lane >> 4) * 4;
#pragma unroll
    for (int i = 0; i < 4; ++i) {
        long row = rowBase + orow + i;
        if (row >= N_NODES) break;
        float dv = dinv[row];
        __half* op = &out[row * EMB + l15];
        op[0]  = __float2half(dv * acc0[i]);
        op[16] = __float2half(dv * acc1[i]);
        op[32] = __float2half(dv * acc2[i]);
        op[48] = __float2half(dv * acc3[i]);
    }
}

// ---------- FUSED agg(layer l) + gemm(layer l+1), BM=32 tile, LDS-staged csr ----------
// The tile's csr slice [row_start[first], row_end[last]) is CONTIGUOUS (see
// alloc_k) -> one coalesced block load into LDS. Agg then never touches global
// csr: ds_read (broadcast) for (src,w), gathers are the only long-latency ops.
__global__ __launch_bounds__(512) void agg_gemm_k(const __half* __restrict__ hs_in,
                                                  const int2* __restrict__ csr,
                                                  const int* __restrict__ row_start,
                                                  const int* __restrict__ row_end,
                                                  const float* __restrict__ dinv,
                                                  const float* __restrict__ b,
                                                  const float* __restrict__ W,
                                                  __half* __restrict__ hs_out) {
    constexpr int K = EMB;       // 64
    constexpr int LDK = K + 8;   // 72
    __shared__ __align__(16) int2 Ecsr[ECAP];
    __shared__ __align__(16) f16 Ao[BM * LDK];
    __shared__ __align__(16) f16 Wt[EMB * LDK];
    int tid = threadIdx.x;
    int wv = tid >> 6, lane = tid & 63;
    long tileBase = (long)blockIdx.x * BM;
    int validRows = (int)min((long)BM, (long)N_NODES - tileBase);

    {   // stage W transposed fp32 -> fp16 (Wt[n][k])
        const float4* Wg = (const float4*)W;
        for (int i = tid; i < K * (EMB / 4); i += 512) {
            int k = i >> 4, nq = i & 15;
            float4 v = Wg[i];
            Wt[(4 * nq + 0) * LDK + k] = (f16)v.x;
            Wt[(4 * nq + 1) * LDK + k] = (f16)v.y;
            Wt[(4 * nq + 2) * LDK + k] = (f16)v.z;
            Wt[(4 * nq + 3) * LDK + k] = (f16)v.w;
        }
    }
    int eBeg = row_start[tileBase];
    int eTot = row_end[tileBase + validRows - 1] - eBeg;
    bool staged = (eTot <= ECAP);
    if (staged) {   // coalesced bulk load of the tile's whole csr slice
        for (int i = tid; i < eTot; i += 512) Ecsr[i] = csr[eBeg + i];
    }
    __syncthreads();
    {   // phase 1: aggregation, 4 nodes per wave, lane = channel
        const char* hsb = (const char*)hs_in + (size_t)(lane * 2);
        float bl = b[lane];
        for (int i = 0; i < 4; ++i) {
            long node = tileBase + wv * 4 + i;
            if (node >= N_NODES) break;
            float di = dinv[node];
            float acc = __half2float(hs_in[node * EMB + lane]);   // self term
            int rs = row_start[node], re = row_end[node];
            if (staged) acc = agg_row(hsb, Ecsr, rs - eBeg, re - eBeg, acc);
            else        acc = agg_row(hsb, csr, rs, re, acc);
            float o = tanhf(di * acc + bl);
            Ao[(wv * 4 + i) * LDK + lane] = (f16)o;
        }
    }
    if (validRows < BM) {   // zero-fill invalid rows (tail block only)
        for (int i = tid; i < (BM - validRows) * (K / 8); i += 512) {
            int r = validRows + i / (K / 8), c = i % (K / 8);
            *(uint4*)&Ao[r * LDK + c * 8] = make_uint4(0, 0, 0, 0);
        }
    }
    __syncthreads();
    {   // phase 2: MFMA 32x64 @ 64x64; one 16x16 tile per wave
        int l15 = lane & 15, kg = (lane >> 4) * 8;
        int r0 = (wv & 1) * 16;
        int c0 = (wv >> 1) * 16;
        const f16* Ap = &Ao[(r0 + l15) * LDK + kg];
        const f16* Bp = &Wt[(c0 + l15) * LDK + kg];
        f32x4 acc = {0.f, 0.f, 0.f, 0.f};
#pragma unroll
        for (int ks = 0; ks < K / 32; ++ks) {
            int k0 = ks * 32;
            half8 a  = *(const half8*)(Ap + k0);
            half8 bb = *(const half8*)(Bp + k0);
            acc = __builtin_amdgcn_mfma_f32_16x16x32_f16(a, bb, acc, 0, 0, 0);
        }
        int orow = r0 + (lane >> 4) * 4;
#pragma unroll
        for (int i = 0; i < 4; ++i) {
            long row = tileBase + orow + i;
            if (row >= N_NODES) break;
            float dv = dinv[row];
            hs_out[row * EMB + c0 + l15] = __float2half(dv * acc[i]);
        }
    }
}

// ---------- pooling helpers ----------
__device__ inline int f2ord(float x) {
    int bb = __float_as_int(x);
    return bb >= 0 ? bb : (bb ^ 0x7fffffff);
}
__device__ inline float ord2f(int k) {
    return __int_as_float(k >= 0 ? k : (k ^ 0x7fffffff));
}

// ---------- FUSED agg(layer 3) + pool, BM=32 tile, LDS-staged csr ----------
__global__ __launch_bounds__(512) void agg_pool_k(const __half* __restrict__ hs_in,
                                                  const int2* __restrict__ csr,
                                                  const int* __restrict__ row_start,
                                                  const int* __restrict__ row_end,
                                                  const float* __restrict__ dinv,
                                                  const float* __restrict__ b,
                                                  const int* __restrict__ batch,
                                                  int* gmax, float* gsum, int* cnt) {
    __shared__ __align__(16) int2 Ecsr[ECAP];
    __shared__ float Ho[BM * EMB];
    int tid = threadIdx.x;
    int wv = tid >> 6, lane = tid & 63;
    long tileBase = (long)blockIdx.x * BM;
    int validRows = (int)min((long)BM, (long)N_NODES - tileBase);

    int eBeg = row_start[tileBase];
    int eTot = row_end[tileBase + validRows - 1] - eBeg;
    bool staged = (eTot <= ECAP);
    if (staged) {
        for (int i = tid; i < eTot; i += 512) Ecsr[i] = csr[eBeg + i];
    }
    __syncthreads();
    {
        const char* hsb = (const char*)hs_in + (size_t)(lane * 2);
        float bl = b[lane];
        for (int i = 0; i < 4; ++i) {
            long node = tileBase + wv * 4 + i;
            if (node >= N_NODES) break;
            float di = dinv[node];
            float acc = __half2float(hs_in[node * EMB + lane]);
            int rs = row_start[node], re = row_end[node];
            if (staged) acc = agg_row(hsb, Ecsr, rs - eBeg, re - eBeg, acc);
            else        acc = agg_row(hsb, csr, rs, re, acc);
            Ho[(wv * 4 + i) * EMB + lane] = tanhf(di * acc + bl);
        }
    }
    __syncthreads();
    if (wv < BM / POOL_CHUNK) {   // waves 0-1 pool the two 16-node chunks
        long start = tileBase + wv * POOL_CHUNK;
        if (start >= N_NODES) return;   // 50000 % 16 == 0 -> full chunks when valid
        int bsel = (lane < POOL_CHUNK) ? batch[start + lane] : 0;
        float v[POOL_CHUNK];
#pragma unroll
        for (int i = 0; i < POOL_CHUNK; ++i)
            v[i] = Ho[(wv * POOL_CHUNK + i) * EMB + lane];
        int curg = __shfl(bsel, 0);
        float mx = -INFINITY, sm = 0.f;
        int ct = 0;
#pragma unroll
        for (int i = 0; i < POOL_CHUNK; ++i) {
            int g = __shfl(bsel, i);
            if (g != curg) {
                atomicMax(&gmax[curg * EMB + lane], f2ord(mx));
                atomicAdd(&gsum[curg * EMB + lane], sm);
                if (lane == 0) atomicAdd(&cnt[curg], ct);
                curg = g; mx = -INFINITY; sm = 0.f; ct = 0;
            }
            mx = fmaxf(mx, v[i]);
            sm += v[i];
            ++ct;
        }
        atomicMax(&gmax[curg * EMB + lane], f2ord(mx));
        atomicAdd(&gsum[curg * EMB + lane], sm);
        if (lane == 0) atomicAdd(&cnt[curg], ct);
    }
}

__global__ void final_k(const int* __restrict__ gmax, const float* __restrict__ gsum,
                        const int* __restrict__ cnt, const float* __restrict__ Wout,
                        const float* __restrict__ bout, float* __restrict__ out) {
    int g = threadIdx.x;
    if (g >= N_GRAPHS) return;
    float c = fmaxf((float)cnt[g], 1.0f);
    float acc = bout[0];
    for (int ch = 0; ch < EMB; ++ch) {
        acc += ord2f(gmax[g * EMB + ch]) * Wout[ch]
             + (gsum[g * EMB + ch] / c) * Wout[EMB + ch];
    }
    out[g] = acc;
}

extern "C" void kernel_launch(void* const* d_in, const int* in_sizes, int n_in,
                              void* d_out, int out_size, void* d_ws, size_t ws_size,
                              hipStream_t stream) {
    const float* x         = (const float*)d_in[0];
    const int*   edge_idx  = (const int*)d_in[1];
    const float* edge_attr = (const float*)d_in[2];
    const int*   batch     = (const int*)d_in[3];
    const float* W0 = (const float*)d_in[4];
    const float* b0 = (const float*)d_in[5];
    const float* W1 = (const float*)d_in[6];
    const float* b1 = (const float*)d_in[7];
    const float* W2 = (const float*)d_in[8];
    const float* b2 = (const float*)d_in[9];
    const float* W3 = (const float*)d_in[10];
    const float* b3 = (const float*)d_in[11];
    const float* Wout = (const float*)d_in[12];
    const float* bout = (const float*)d_in[13];
    float* out = (float*)d_out;

    const int* src = edge_idx;            // edge_index[0]
    const int* dst = edge_idx + N_EDGES;  // edge_index[1]

    // workspace layout (~33 MB)
    char* ws = (char*)d_ws;
    float*  dinv      = (float*)ws;  ws += (size_t)N_NODES * sizeof(float);
    unsigned long long* cnt64 = (unsigned long long*)ws;
    ws += (size_t)N_NODES * CPAD64 * sizeof(unsigned long long);
    int*    row_start = (int*)ws;    ws += (size_t)N_NODES * sizeof(int);
    int*    row_end   = (int*)ws;    ws += (size_t)N_NODES * sizeof(int);
    int*    slot_in   = (int*)ws;    ws += (size_t)N_EDGES * sizeof(int);
    int*    total     = (int*)ws;    ws += 4 * sizeof(int);  // keep 16B alignment
    int2*   csr       = (int2*)ws;   ws += (size_t)N_EDGES * sizeof(int2);
    __half* bufL      = (__half*)ws; ws += (size_t)N_NODES * EMB * sizeof(__half);
    __half* bufM      = (__half*)ws; ws += (size_t)N_NODES * EMB * sizeof(__half);
    int*    gmax      = (int*)ws;    ws += N_GRAPHS * EMB * sizeof(int);
    float*  gsum      = (float*)ws;  ws += N_GRAPHS * EMB * sizeof(float);
    int*    cnt       = (int*)ws;    ws += N_GRAPHS * sizeof(int);

    const int nodeB  = (N_NODES + 255) / 256;
    const int edgeB  = (N_EDGES + 255) / 256;
    const int gemm0B = (N_NODES + 63) / 64;      // 782 blocks, 64-node tiles
    const int fuseB  = (N_NODES + BM - 1) / BM;  // 1563 blocks, 32-node tiles
    const int initB  = (N_NODES * CPAD64 + 255) / 256;

    // CSR precompute (norm fully folded; count+weighted-degree via ONE 64b atomic)
    init_k<<<initB, 256, 0, stream>>>(cnt64, total, gmax, gsum, cnt);
    hist_k<<<edgeB, 256, 0, stream>>>(dst, edge_attr, cnt64, slot_in);
    alloc_k<<<nodeB, 256, 0, stream>>>(cnt64, row_start, row_end, total, dinv);
    scatter_k<<<edgeB, 256, 0, stream>>>(src, dst, edge_attr, slot_in, row_start, csr);

    // layer pipeline: gemm0, then fused agg_l+gemm_{l+1}, then fused agg3+pool
    gemm_k<IN_CH, false><<<gemm0B, 256, 0, stream>>>(x, W0, dinv, bufL);
    agg_gemm_k<<<fuseB, 512, 0, stream>>>(bufL, csr, row_start, row_end, dinv, b0, W1, bufM);
    agg_gemm_k<<<fuseB, 512, 0, stream>>>(bufM, csr, row_start, row_end, dinv, b1, W2, bufL);
    agg_gemm_k<<<fuseB, 512, 0, stream>>>(bufL, csr, row_start, row_end, dinv, b2, W3, bufM);
    agg_pool_k<<<fuseB, 512, 0, stream>>>(bufM, csr, row_start, row_end, dinv, b3,
                                          batch, gmax, gsum, cnt);
    final_k<<<1, 64, 0, stream>>>(gmax, gsum, cnt, Wout, bout, out);
}